// Round 1
// baseline (1762.759 us; speedup 1.0000x reference)
//
#include <hip/hip_runtime.h>

#define N_NODES 100000
#define N_EDGES 300000
#define HID 256

// ---------------- output layout (floats) ----------------
#define H_OFF   0
#define CP_OFF  25600000
#define VL_OFF  28800000
#define BL_OFF  29600000
#define VI_OFF  30800000

// ============ kernel 1: per-atom-type valence MLP + h0 rows ============
__global__ void k_type_mlp(const float* __restrict__ atom_emb,
                           const float* __restrict__ vp_w1, const float* __restrict__ vp_b1,
                           const float* __restrict__ vp_w2, const float* __restrict__ vp_b2,
                           int* __restrict__ pv_tab, float* __restrict__ vl_tab,
                           float* __restrict__ h0_tab)
{
    int tid = threadIdx.x;
    for (int i = tid; i < 11 * 256; i += 256) h0_tab[i] = 0.f;
    __syncthreads();
    if (tid < 11) {
        int t = tid;
        const float* ae = atom_emb + t * 64;
        float lg[8];
        #pragma unroll
        for (int c = 0; c < 8; ++c) lg[c] = vp_b2[c];
        for (int j = 0; j < 32; ++j) {
            float z = vp_b1[j];
            for (int d = 0; d < 64; ++d) z += ae[d] * vp_w1[d * 32 + j];
            z = fmaxf(z, 0.f);
            #pragma unroll
            for (int c = 0; c < 8; ++c) lg[c] += z * vp_w2[j * 8 + c];
        }
        int best = 0;
        #pragma unroll
        for (int c = 1; c < 8; ++c) if (lg[c] > lg[best]) best = c;  // first-max tie-break
        pv_tab[t] = best + 1;
        for (int c = 0; c < 8; ++c) vl_tab[t * 8 + c] = lg[c];
        float* h0 = h0_tab + t * 256;
        for (int d = 0; d < 64; ++d) h0[d] = ae[d];
        h0[64 + best] = 1.f;
    }
}

// ============ kernel 1b: layer-0 tables + bond tables for layers 1,2 ============
// grid: 11 (self0) + 55 (msg0) + 10 (bondtab l=1,2) = 76 blocks, 256 threads
__global__ void k_tables(const float* __restrict__ bond_emb,
                         const float* __restrict__ gnn_wself, const float* __restrict__ gnn_bself,
                         const float* __restrict__ gnn_wmsg, const float* __restrict__ gnn_bmsg,
                         const float* __restrict__ h0_tab,
                         float* __restrict__ self0_tab, float* __restrict__ msg0_tab,
                         float* __restrict__ bondtab)
{
    int b = blockIdx.x, c = threadIdx.x;
    if (b < 11) {
        int t = b;
        const float* h0 = h0_tab + t * 256;
        float acc = gnn_bself[c];
        for (int k = 0; k < 256; ++k) acc += h0[k] * gnn_wself[k * 256 + c];
        self0_tab[t * 256 + c] = acc;
    } else if (b < 66) {
        int idx = b - 11; int t = idx / 5, bb = idx % 5;
        const float* h0 = h0_tab + t * 256;
        float acc = gnn_bmsg[c];
        for (int k = 0; k < 256; ++k) acc += h0[k] * gnn_wmsg[k * 256 + c];
        const float* be = bond_emb + bb * 64;
        for (int k = 0; k < 64; ++k) acc += be[k] * gnn_wmsg[(256 + k) * 256 + c];
        msg0_tab[idx * 256 + c] = fmaxf(acc, 0.f);
    } else {
        int idx = b - 66; int l = idx / 5 + 1, bb = idx % 5;
        const float* w = gnn_wmsg + l * 320 * 256;
        const float* be = bond_emb + bb * 64;
        float acc = gnn_bmsg[l * 256 + c];
        for (int k = 0; k < 64; ++k) acc += be[k] * w[(256 + k) * 256 + c];
        bondtab[(l - 1) * 5 * 256 + bb * 256 + c] = acc;
    }
}

// ============ node init: types, pv, valence_logits out, zero degree ============
__global__ void k_node_init(const float* __restrict__ x, const int* __restrict__ pv_tab,
                            const float* __restrict__ vl_tab,
                            int* __restrict__ types, int* __restrict__ pvarr,
                            int* __restrict__ degree, float* __restrict__ vl_out)
{
    int i = blockIdx.x * blockDim.x + threadIdx.x;
    if (i >= N_NODES) return;
    int t = (int)x[i * 16];
    t = min(max(t, 0), 10);
    types[i] = t;
    pvarr[i] = pv_tab[t];
    degree[i] = 0;
    float4 v0 = *(const float4*)&vl_tab[t * 8];
    float4 v1 = *(const float4*)&vl_tab[t * 8 + 4];
    *(float4*)&vl_out[i * 8]     = v0;
    *(float4*)&vl_out[i * 8 + 4] = v1;
}

__global__ void k_edge_deg(const int* __restrict__ ei, int* __restrict__ degree)
{
    int e = blockIdx.x * blockDim.x + threadIdx.x;
    if (e >= N_EDGES) return;
    atomicAdd(&degree[ei[e]], 1);
}

// ============ scan (exclusive prefix sum of degree) ============
#define SCAN_B 1024
__global__ void k_scan1(const int* __restrict__ degree, int* __restrict__ part, int* __restrict__ bsum)
{
    __shared__ int s[SCAN_B];
    int tid = threadIdx.x;
    int i = blockIdx.x * SCAN_B + tid;
    int v = (i < N_NODES) ? degree[i] : 0;
    s[tid] = v; __syncthreads();
    for (int off = 1; off < SCAN_B; off <<= 1) {
        int t = (tid >= off) ? s[tid - off] : 0;
        __syncthreads();
        s[tid] += t;
        __syncthreads();
    }
    if (i < N_NODES) part[i] = s[tid] - v;
    if (tid == SCAN_B - 1) bsum[blockIdx.x] = s[tid];
}

__global__ void k_scan2(const int* __restrict__ bsum, int* __restrict__ bbase, int nb)
{
    __shared__ int s[128];
    int tid = threadIdx.x;
    int v = (tid < nb) ? bsum[tid] : 0;
    s[tid] = v; __syncthreads();
    for (int off = 1; off < 128; off <<= 1) {
        int t = (tid >= off) ? s[tid - off] : 0;
        __syncthreads();
        s[tid] += t;
        __syncthreads();
    }
    bbase[tid] = s[tid] - v;
}

__global__ void k_scan3(int* __restrict__ part, const int* __restrict__ bbase, int* __restrict__ cursor)
{
    int i = blockIdx.x * SCAN_B + threadIdx.x;
    if (i >= N_NODES) return;
    int o = part[i] + bbase[blockIdx.x];
    part[i] = o;
    cursor[i] = o;
}

// ============ CSR fill: csr[pos] = col | bt<<20 | type[col]<<24 ============
__global__ void k_csr_fill(const int* __restrict__ ei, const float* __restrict__ edge_attr,
                           const int* __restrict__ types, int* __restrict__ cursor,
                           int* __restrict__ csr)
{
    int e = blockIdx.x * blockDim.x + threadIdx.x;
    if (e >= N_EDGES) return;
    int row = ei[e], col = ei[N_EDGES + e];
    int bt = (int)edge_attr[e * 4];
    bt = min(max(bt, 0), 4);
    int pos = atomicAdd(&cursor[row], 1);
    csr[pos] = col | (bt << 20) | (types[col] << 24);
}

// ============ layer-0 aggregation: pure table lookups ============
__global__ __launch_bounds__(256) void k_agg0(const int* __restrict__ offsets, const int* __restrict__ degree,
                       const int* __restrict__ types,
                       const float* __restrict__ self0_tab, const float* __restrict__ msg0_tab,
                       const int* __restrict__ csr, float* __restrict__ h)
{
    int wid = threadIdx.x >> 6, lane = threadIdx.x & 63;
    int node = blockIdx.x * 4 + wid;
    if (node >= N_NODES) return;
    int t = types[node];
    float4 acc = *(const float4*)&self0_tab[t * 256 + lane * 4];
    int start = offsets[node], deg = degree[node];
    for (int j = 0; j < deg; ++j) {
        int p = csr[start + j];
        int combo = ((p >> 24) & 0xF) * 5 + ((p >> 20) & 7);
        float4 m = *(const float4*)&msg0_tab[combo * 256 + lane * 4];
        acc.x += m.x; acc.y += m.y; acc.z += m.z; acc.w += m.w;
    }
    float4 r;
    r.x = fmaxf(acc.x, 0.f); r.y = fmaxf(acc.y, 0.f);
    r.z = fmaxf(acc.z, 0.f); r.w = fmaxf(acc.w, 0.f);
    *(float4*)&h[node * 256 + lane * 4] = r;
}

// ============ layers 1,2 aggregation: h = relu(hs + sum relu(hm[col]+bondtab[bt])) ============
__global__ __launch_bounds__(256) void k_agg12(const int* __restrict__ offsets, const int* __restrict__ degree,
                        const float* __restrict__ hs, const float* __restrict__ hm,
                        const float* __restrict__ bondtab, const int* __restrict__ csr,
                        float* __restrict__ h)
{
    int wid = threadIdx.x >> 6, lane = threadIdx.x & 63;
    int node = blockIdx.x * 4 + wid;
    if (node >= N_NODES) return;
    float4 acc = *(const float4*)&hs[node * 256 + lane * 4];
    int start = offsets[node], deg = degree[node];
    for (int j = 0; j < deg; ++j) {
        int p = csr[start + j];
        int c = p & 0xFFFFF;
        int bt = (p >> 20) & 7;
        float4 m = *(const float4*)&hm[c * 256 + lane * 4];
        float4 bb = *(const float4*)&bondtab[bt * 256 + lane * 4];
        acc.x += fmaxf(m.x + bb.x, 0.f);
        acc.y += fmaxf(m.y + bb.y, 0.f);
        acc.z += fmaxf(m.z + bb.z, 0.f);
        acc.w += fmaxf(m.w + bb.w, 0.f);
    }
    float4 r;
    r.x = fmaxf(acc.x, 0.f); r.y = fmaxf(acc.y, 0.f);
    r.z = fmaxf(acc.z, 0.f); r.w = fmaxf(acc.w, 0.f);
    *(float4*)&h[node * 256 + lane * 4] = r;
}

// ============ violations + damping; writes final h into d_out ============
__global__ void k_damp(const float* __restrict__ h, const int* __restrict__ degree,
                       const int* __restrict__ pvarr,
                       float* __restrict__ h_out, float* __restrict__ viol_out)
{
    int idx = blockIdx.x * blockDim.x + threadIdx.x;
    if (idx >= N_NODES * 64) return;
    int i = idx >> 6, q = idx & 63;
    float viol = fmaxf((float)degree[i] - (float)pvarr[i], 0.f);
    float s = 1.f / (1.f + viol);
    float4 v = *(const float4*)&h[i * 256 + q * 4];
    v.x *= s; v.y *= s; v.z *= s; v.w *= s;
    *(float4*)&h_out[i * 256 + q * 4] = v;
    if (q == 0) viol_out[i] = viol;
}

// ============ generic fp32 tiled GEMM: C = op(A[M,K] @ B[K,N] + bias) ============
#define BM 128
#define BN 64
#define BK 16
__global__ __launch_bounds__(256) void k_gemm(const float* __restrict__ A, int lda,
    const float* __restrict__ B, int ldb, const float* __restrict__ bias,
    float* __restrict__ C, int ldc, int M, int N, int K, int do_relu)
{
    __shared__ float As[BK][BM];
    __shared__ float Bs[BK][BN];
    int tid = threadIdx.x;
    int bm = blockIdx.x * BM, bn = blockIdx.y * BN;
    int tx = tid & 15, ty = tid >> 4;
    float acc[8][4];
    #pragma unroll
    for (int i = 0; i < 8; ++i)
        #pragma unroll
        for (int j = 0; j < 4; ++j) acc[i][j] = 0.f;

    int ar = tid >> 1;          // 0..127
    int ak = (tid & 1) * 8;     // 0 or 8
    int bk = tid >> 4;          // 0..15
    int bn4 = (tid & 15) * 4;   // 0..60

    for (int k0 = 0; k0 < K; k0 += BK) {
        float4 a0 = make_float4(0.f, 0.f, 0.f, 0.f), a1 = a0, b0 = a0;
        if (bm + ar < M) {
            const float* ap = A + (size_t)(bm + ar) * lda + k0 + ak;
            a0 = *(const float4*)ap;
            a1 = *(const float4*)(ap + 4);
        }
        if (bn + bn4 < N) {
            b0 = *(const float4*)(B + (size_t)(k0 + bk) * ldb + bn + bn4);
        }
        __syncthreads();
        As[ak + 0][ar] = a0.x; As[ak + 1][ar] = a0.y; As[ak + 2][ar] = a0.z; As[ak + 3][ar] = a0.w;
        As[ak + 4][ar] = a1.x; As[ak + 5][ar] = a1.y; As[ak + 6][ar] = a1.z; As[ak + 7][ar] = a1.w;
        *(float4*)&Bs[bk][bn4] = b0;
        __syncthreads();
        #pragma unroll
        for (int kk = 0; kk < BK; ++kk) {
            float4 av0 = *(const float4*)&As[kk][ty * 8];
            float4 av1 = *(const float4*)&As[kk][ty * 8 + 4];
            float4 bv  = *(const float4*)&Bs[kk][tx * 4];
            float a[8] = {av0.x, av0.y, av0.z, av0.w, av1.x, av1.y, av1.z, av1.w};
            float bb[4] = {bv.x, bv.y, bv.z, bv.w};
            #pragma unroll
            for (int i = 0; i < 8; ++i)
                #pragma unroll
                for (int j = 0; j < 4; ++j) acc[i][j] += a[i] * bb[j];
        }
    }
    if (bn + tx * 4 < N) {
        float4 bias4 = make_float4(0.f, 0.f, 0.f, 0.f);
        if (bias) bias4 = *(const float4*)&bias[bn + tx * 4];
        #pragma unroll
        for (int i = 0; i < 8; ++i) {
            int m = bm + ty * 8 + i;
            if (m < M) {
                float4 c;
                c.x = acc[i][0] + bias4.x; c.y = acc[i][1] + bias4.y;
                c.z = acc[i][2] + bias4.z; c.w = acc[i][3] + bias4.w;
                if (do_relu) {
                    c.x = fmaxf(c.x, 0.f); c.y = fmaxf(c.y, 0.f);
                    c.z = fmaxf(c.z, 0.f); c.w = fmaxf(c.w, 0.f);
                }
                *(float4*)&C[(size_t)m * ldc + bn + tx * 4] = c;
            }
        }
    }
}

// ============ bond t1: T1[e,128] = relu(u[row]+v[col]+pvr*w512+pvc*w513) ============
__global__ void k_bond_t1(const int* __restrict__ ei, const int* __restrict__ pvarr,
                          const float* __restrict__ u, const float* __restrict__ v,
                          const float* __restrict__ bc_w1, float* __restrict__ T1,
                          int e0, int ecnt)
{
    int idx = blockIdx.x * blockDim.x + threadIdx.x;
    if (idx >= ecnt * 32) return;
    int el = idx >> 5, q = idx & 31;
    int e = e0 + el;
    int row = ei[e], col = ei[N_EDGES + e];
    float pvr = (float)pvarr[row], pvc = (float)pvarr[col];
    float4 uu = *(const float4*)&u[row * 128 + q * 4];
    float4 vv = *(const float4*)&v[col * 128 + q * 4];
    float4 w5 = *(const float4*)&bc_w1[512 * 128 + q * 4];
    float4 w6 = *(const float4*)&bc_w1[513 * 128 + q * 4];
    float4 t;
    t.x = fmaxf(uu.x + vv.x + pvr * w5.x + pvc * w6.x, 0.f);
    t.y = fmaxf(uu.y + vv.y + pvr * w5.y + pvc * w6.y, 0.f);
    t.z = fmaxf(uu.z + vv.z + pvr * w5.z + pvc * w6.z, 0.f);
    t.w = fmaxf(uu.w + vv.w + pvr * w5.w + pvc * w6.w, 0.f);
    *(float4*)&T1[el * 128 + q * 4] = t;
}

// ============ bond out: bl = T2 @ W3 + b3 + penalties ============
__global__ __launch_bounds__(256) void k_bond_out(const float* __restrict__ T2, const int* __restrict__ ei,
                           const int* __restrict__ types, const int* __restrict__ pvarr,
                           const float* __restrict__ bc_w3, const float* __restrict__ bc_b3,
                           float* __restrict__ bl_out, int e0, int ecnt)
{
    __shared__ float W3s[256];
    __shared__ float b3s[4];
    int tid = threadIdx.x;
    W3s[tid] = bc_w3[tid];
    if (tid < 4) b3s[tid] = bc_b3[tid];
    __syncthreads();
    int el = blockIdx.x * blockDim.x + tid;
    if (el >= ecnt) return;
    int e = e0 + el;
    const float* t2 = T2 + el * 64;
    float a0 = b3s[0], a1 = b3s[1], a2 = b3s[2], a3 = b3s[3];
    for (int k = 0; k < 64; k += 4) {
        float4 t = *(const float4*)&t2[k];
        a0 += t.x * W3s[(k + 0) * 4 + 0]; a1 += t.x * W3s[(k + 0) * 4 + 1];
        a2 += t.x * W3s[(k + 0) * 4 + 2]; a3 += t.x * W3s[(k + 0) * 4 + 3];
        a0 += t.y * W3s[(k + 1) * 4 + 0]; a1 += t.y * W3s[(k + 1) * 4 + 1];
        a2 += t.y * W3s[(k + 1) * 4 + 2]; a3 += t.y * W3s[(k + 1) * 4 + 3];
        a0 += t.z * W3s[(k + 2) * 4 + 0]; a1 += t.z * W3s[(k + 2) * 4 + 1];
        a2 += t.z * W3s[(k + 2) * 4 + 2]; a3 += t.z * W3s[(k + 2) * 4 + 3];
        a0 += t.w * W3s[(k + 3) * 4 + 0]; a1 += t.w * W3s[(k + 3) * 4 + 1];
        a2 += t.w * W3s[(k + 3) * 4 + 2]; a3 += t.w * W3s[(k + 3) * 4 + 3];
    }
    int row = ei[e], col = ei[N_EDGES + e];
    int tr = types[row], tc = types[col];
    int pr = pvarr[row], pc = pvarr[col];
    float halogen = (tr == 4 || tr == 5 || tc == 4 || tc == 5) ? 1.f : 0.f;
    float l1 = (pr <= 1 || pc <= 1) ? 1.f : 0.f;
    float l2 = (pr <= 2 || pc <= 2) ? 1.f : 0.f;
    float pen13 = -100.f * halogen - 50.f * l1;
    a1 += pen13;
    a3 += pen13;
    a2 += pen13 - 50.f * l2;
    float4 o = make_float4(a0, a1, a2, a3);
    *(float4*)&bl_out[(size_t)e * 4] = o;
}

// ================================================================
extern "C" void kernel_launch(void* const* d_in, const int* in_sizes, int n_in,
                              void* d_out, int out_size, void* d_ws, size_t ws_size,
                              hipStream_t stream)
{
    const float* x          = (const float*)d_in[0];
    const float* edge_attr  = (const float*)d_in[1];
    const float* atom_emb   = (const float*)d_in[2];
    const float* bond_emb   = (const float*)d_in[3];
    const float* vp_w1      = (const float*)d_in[4];
    const float* vp_b1      = (const float*)d_in[5];
    const float* vp_w2      = (const float*)d_in[6];
    const float* vp_b2      = (const float*)d_in[7];
    const float* gnn_wself  = (const float*)d_in[8];
    const float* gnn_bself  = (const float*)d_in[9];
    const float* gnn_wmsg   = (const float*)d_in[10];
    const float* gnn_bmsg   = (const float*)d_in[11];
    const float* bc_w1      = (const float*)d_in[12];
    const float* bc_b1      = (const float*)d_in[13];
    const float* bc_w2      = (const float*)d_in[14];
    const float* bc_b2      = (const float*)d_in[15];
    const float* bc_w3      = (const float*)d_in[16];
    const float* bc_b3      = (const float*)d_in[17];
    const float* cp_w1      = (const float*)d_in[18];
    const float* cp_b1      = (const float*)d_in[19];
    const float* cp_w2      = (const float*)d_in[20];
    const float* cp_b2      = (const float*)d_in[21];
    const int*   ei         = (const int*)d_in[22];

    float* out    = (float*)d_out;
    float* h_out  = out + H_OFF;
    float* cp_out = out + CP_OFF;
    float* vl_out = out + VL_OFF;
    float* bl_out = out + BL_OFF;
    float* vi_out = out + VI_OFF;

    char* w = (char*)d_ws;
    float* h_ws  = (float*)w; w += (size_t)25600000 * 4;   // also reused for T1/T2 chunks
    float* hm_ws = (float*)w; w += (size_t)25600000 * 4;   // hm; later u|v; later t1cp
    int* degree  = (int*)w; w += (size_t)N_NODES * 4;
    int* offsets = (int*)w; w += (size_t)N_NODES * 4;
    int* cursor  = (int*)w; w += (size_t)N_NODES * 4;
    int* types   = (int*)w; w += (size_t)N_NODES * 4;
    int* pvarr   = (int*)w; w += (size_t)N_NODES * 4;
    int* csr     = (int*)w; w += (size_t)N_EDGES * 4;
    int* bsum    = (int*)w; w += 1024;
    int* bbase   = (int*)w; w += 1024;
    int* pv_tab  = (int*)w; w += 256;
    float* vl_tab    = (float*)w; w += 512;
    float* h0_tab    = (float*)w; w += 11 * 256 * 4;
    float* self0_tab = (float*)w; w += 11 * 256 * 4;
    float* msg0_tab  = (float*)w; w += 55 * 256 * 4;
    float* bondtab   = (float*)w; w += 2 * 5 * 256 * 4;

    k_type_mlp<<<1, 256, 0, stream>>>(atom_emb, vp_w1, vp_b1, vp_w2, vp_b2, pv_tab, vl_tab, h0_tab);
    k_tables<<<76, 256, 0, stream>>>(bond_emb, gnn_wself, gnn_bself, gnn_wmsg, gnn_bmsg,
                                     h0_tab, self0_tab, msg0_tab, bondtab);
    k_node_init<<<(N_NODES + 255) / 256, 256, 0, stream>>>(x, pv_tab, vl_tab, types, pvarr, degree, vl_out);
    k_edge_deg<<<(N_EDGES + 255) / 256, 256, 0, stream>>>(ei, degree);
    int nb = (N_NODES + SCAN_B - 1) / SCAN_B;  // 98
    k_scan1<<<nb, SCAN_B, 0, stream>>>(degree, offsets, bsum);
    k_scan2<<<1, 128, 0, stream>>>(bsum, bbase, nb);
    k_scan3<<<nb, SCAN_B, 0, stream>>>(offsets, bbase, cursor);
    k_csr_fill<<<(N_EDGES + 255) / 256, 256, 0, stream>>>(ei, edge_attr, types, cursor, csr);
    k_agg0<<<N_NODES / 4, 256, 0, stream>>>(offsets, degree, types, self0_tab, msg0_tab, csr, h_ws);

    for (int l = 1; l <= 2; ++l) {
        const float* Wm = gnn_wmsg + (size_t)l * 320 * 256;
        const float* Ws = gnn_wself + (size_t)l * 256 * 256;
        const float* bs = gnn_bself + (size_t)l * 256;
        dim3 g((N_NODES + BM - 1) / BM, 256 / BN);
        // hm = h @ Wm_top  (no bias)
        k_gemm<<<g, 256, 0, stream>>>(h_ws, 256, Wm, 256, nullptr, hm_ws, 256, N_NODES, 256, 256, 0);
        // hs = h @ Ws + bself  -> staged in d_out h region (overwritten later by damp)
        k_gemm<<<g, 256, 0, stream>>>(h_ws, 256, Ws, 256, bs, h_out, 256, N_NODES, 256, 256, 0);
        k_agg12<<<N_NODES / 4, 256, 0, stream>>>(offsets, degree, h_out, hm_ws,
                                                 bondtab + (size_t)(l - 1) * 5 * 256, csr, h_ws);
    }

    k_damp<<<(N_NODES * 64 + 255) / 256, 256, 0, stream>>>(h_ws, degree, pvarr, h_out, vi_out);

    // bond prediction
    float* u = hm_ws;
    float* v = hm_ws + (size_t)N_NODES * 128;
    {
        dim3 g((N_NODES + BM - 1) / BM, 128 / BN);
        k_gemm<<<g, 256, 0, stream>>>(h_out, 256, bc_w1, 128, bc_b1, u, 128, N_NODES, 128, 256, 0);
        k_gemm<<<g, 256, 0, stream>>>(h_out, 256, bc_w1 + 256 * 128, 128, nullptr, v, 128, N_NODES, 128, 256, 0);
    }
    float* T1 = h_ws;
    float* T2 = h_ws + (size_t)9600000;
    const int ECH = 75000;
    for (int c = 0; c < 4; ++c) {
        int e0 = c * ECH;
        k_bond_t1<<<(ECH * 32 + 255) / 256, 256, 0, stream>>>(ei, pvarr, u, v, bc_w1, T1, e0, ECH);
        dim3 g2((ECH + BM - 1) / BM, 1);
        k_gemm<<<g2, 256, 0, stream>>>(T1, 128, bc_w2, 64, bc_b2, T2, 64, ECH, 64, 128, 1);
        k_bond_out<<<(ECH + 255) / 256, 256, 0, stream>>>(T2, ei, types, pvarr, bc_w3, bc_b3, bl_out, e0, ECH);
    }

    // chem props
    float* t1cp = hm_ws;
    {
        dim3 g((N_NODES + BM - 1) / BM, 128 / BN);
        k_gemm<<<g, 256, 0, stream>>>(h_out, 256, cp_w1, 128, cp_b1, t1cp, 128, N_NODES, 128, 256, 1);
        dim3 g2((N_NODES + BM - 1) / BM, 1);
        k_gemm<<<g2, 256, 0, stream>>>(t1cp, 128, cp_w2, 32, cp_b2, cp_out, 32, N_NODES, 32, 128, 0);
    }
}

// Round 2
// 929.505 us; speedup vs baseline: 1.8964x; 1.8964x over previous
//
#include <hip/hip_runtime.h>

#define N_NODES 100000
#define N_EDGES 300000
#define M_PAD   100096   // 782*128

typedef unsigned short u16;
typedef short bf16x8 __attribute__((ext_vector_type(8)));
typedef float f32x4  __attribute__((ext_vector_type(4)));

__device__ __forceinline__ float bf2f(u16 u) {
    unsigned x = ((unsigned)u) << 16;
    return __builtin_bit_cast(float, x);
}
__device__ __forceinline__ u16 f2bf(float f) {
    unsigned u = __builtin_bit_cast(unsigned, f);
    unsigned r = (u + 0x7FFF + ((u >> 16) & 1)) >> 16;
    return (u16)r;
}

// ---------------- output layout (floats) ----------------
#define H_OFF   0
#define CP_OFF  25600000
#define VL_OFF  28800000
#define BL_OFF  29600000
#define VI_OFF  30800000

// ============ per-atom-type valence MLP + h0 rows ============
__global__ void k_type_mlp(const float* __restrict__ atom_emb,
                           const float* __restrict__ vp_w1, const float* __restrict__ vp_b1,
                           const float* __restrict__ vp_w2, const float* __restrict__ vp_b2,
                           int* __restrict__ pv_tab, float* __restrict__ vl_tab,
                           float* __restrict__ h0_tab)
{
    int tid = threadIdx.x;
    for (int i = tid; i < 11 * 256; i += 256) h0_tab[i] = 0.f;
    __syncthreads();
    if (tid < 11) {
        int t = tid;
        const float* ae = atom_emb + t * 64;
        float lg[8];
        #pragma unroll
        for (int c = 0; c < 8; ++c) lg[c] = vp_b2[c];
        for (int j = 0; j < 32; ++j) {
            float z = vp_b1[j];
            for (int d = 0; d < 64; ++d) z += ae[d] * vp_w1[d * 32 + j];
            z = fmaxf(z, 0.f);
            #pragma unroll
            for (int c = 0; c < 8; ++c) lg[c] += z * vp_w2[j * 8 + c];
        }
        int best = 0;
        #pragma unroll
        for (int c = 1; c < 8; ++c) if (lg[c] > lg[best]) best = c;
        pv_tab[t] = best + 1;
        for (int c = 0; c < 8; ++c) vl_tab[t * 8 + c] = lg[c];
        float* h0 = h0_tab + t * 256;
        for (int d = 0; d < 64; ++d) h0[d] = ae[d];
        h0[64 + best] = 1.f;
    }
}

// ============ layer-0 tables + bond tables for layers 1,2 ============
__global__ void k_tables(const float* __restrict__ bond_emb,
                         const float* __restrict__ gnn_wself, const float* __restrict__ gnn_bself,
                         const float* __restrict__ gnn_wmsg, const float* __restrict__ gnn_bmsg,
                         const float* __restrict__ h0_tab,
                         float* __restrict__ self0_tab, float* __restrict__ msg0_tab,
                         float* __restrict__ bondtab)
{
    int b = blockIdx.x, c = threadIdx.x;
    if (b < 11) {
        int t = b;
        const float* h0 = h0_tab + t * 256;
        float acc = gnn_bself[c];
        for (int k = 0; k < 256; ++k) acc += h0[k] * gnn_wself[k * 256 + c];
        self0_tab[t * 256 + c] = acc;
    } else if (b < 66) {
        int idx = b - 11; int t = idx / 5, bb = idx % 5;
        const float* h0 = h0_tab + t * 256;
        float acc = gnn_bmsg[c];
        for (int k = 0; k < 256; ++k) acc += h0[k] * gnn_wmsg[k * 256 + c];
        const float* be = bond_emb + bb * 64;
        for (int k = 0; k < 64; ++k) acc += be[k] * gnn_wmsg[(256 + k) * 256 + c];
        msg0_tab[idx * 256 + c] = fmaxf(acc, 0.f);
    } else {
        int idx = b - 66; int l = idx / 5 + 1, bb = idx % 5;
        const float* w = gnn_wmsg + (size_t)l * 320 * 256;
        const float* be = bond_emb + bb * 64;
        float acc = gnn_bmsg[l * 256 + c];
        for (int k = 0; k < 64; ++k) acc += be[k] * w[(256 + k) * 256 + c];
        bondtab[(l - 1) * 5 * 256 + bb * 256 + c] = acc;
    }
}

// ============ bf16-transposed weight tables ============
// BtL1/BtL2: [512][256]  (rows 0..255 = Wmsg_top^T, rows 256..511 = Wself^T)
// BtUV: [256][256] (rows 0..127 = bc_w1[0:256]^T, rows 128..255 = bc_w1[256:512]^T)
// BtCP: [128][256] = cp_w1^T
__global__ void k_wtrans(const float* __restrict__ wmsg, const float* __restrict__ wself,
                         const float* __restrict__ bcw1, const float* __restrict__ cpw1,
                         u16* __restrict__ BtL1, u16* __restrict__ BtL2,
                         u16* __restrict__ BtUV, u16* __restrict__ BtCP)
{
    int b = blockIdx.x, k = threadIdx.x;
    if (b < 512) {
        int n = b;
        float v = (n < 256) ? wmsg[(size_t)1 * 320 * 256 + (size_t)k * 256 + n]
                            : wself[(size_t)1 * 256 * 256 + (size_t)k * 256 + (n - 256)];
        BtL1[n * 256 + k] = f2bf(v);
    } else if (b < 1024) {
        int n = b - 512;
        float v = (n < 256) ? wmsg[(size_t)2 * 320 * 256 + (size_t)k * 256 + n]
                            : wself[(size_t)2 * 256 * 256 + (size_t)k * 256 + (n - 256)];
        BtL2[n * 256 + k] = f2bf(v);
    } else if (b < 1280) {
        int n = b - 1024;
        float v = (n < 128) ? bcw1[k * 128 + n] : bcw1[(256 + k) * 128 + (n - 128)];
        BtUV[n * 256 + k] = f2bf(v);
    } else {
        int n = b - 1280;
        BtCP[n * 256 + k] = f2bf(cpw1[k * 128 + n]);
    }
}

// bias512[l][c]: 0 for c<256 (bmsg folded into bondtab), bself for c>=256; biasUV = [bc_b1 | 0]
__global__ void k_setup_bias(const float* __restrict__ bself, const float* __restrict__ bcb1,
                             float* __restrict__ bias512, float* __restrict__ biasUV)
{
    int i = blockIdx.x * 256 + threadIdx.x;
    if (i < 1024) {
        int l = i >> 9, c = i & 511;
        bias512[l * 512 + c] = (c < 256) ? 0.f : bself[(l + 1) * 256 + (c - 256)];
    } else if (i < 1280) {
        int c = i - 1024;
        biasUV[c] = (c < 128) ? bcb1[c] : 0.f;
    }
}

// ============ node init ============
__global__ void k_node_init(const float* __restrict__ x, const int* __restrict__ pv_tab,
                            const float* __restrict__ vl_tab,
                            int* __restrict__ types, int* __restrict__ pvarr,
                            int* __restrict__ degree, float* __restrict__ vl_out)
{
    int i = blockIdx.x * blockDim.x + threadIdx.x;
    if (i >= N_NODES) return;
    int t = (int)x[i * 16];
    t = min(max(t, 0), 10);
    types[i] = t;
    pvarr[i] = pv_tab[t];
    degree[i] = 0;
    float4 v0 = *(const float4*)&vl_tab[t * 8];
    float4 v1 = *(const float4*)&vl_tab[t * 8 + 4];
    *(float4*)&vl_out[i * 8]     = v0;
    *(float4*)&vl_out[i * 8 + 4] = v1;
}

__global__ void k_edge_deg(const int* __restrict__ ei, int* __restrict__ degree)
{
    int e = blockIdx.x * blockDim.x + threadIdx.x;
    if (e >= N_EDGES) return;
    atomicAdd(&degree[ei[e]], 1);
}

// ============ scan ============
#define SCAN_B 1024
__global__ void k_scan1(const int* __restrict__ degree, int* __restrict__ part, int* __restrict__ bsum)
{
    __shared__ int s[SCAN_B];
    int tid = threadIdx.x;
    int i = blockIdx.x * SCAN_B + tid;
    int v = (i < N_NODES) ? degree[i] : 0;
    s[tid] = v; __syncthreads();
    for (int off = 1; off < SCAN_B; off <<= 1) {
        int t = (tid >= off) ? s[tid - off] : 0;
        __syncthreads();
        s[tid] += t;
        __syncthreads();
    }
    if (i < N_NODES) part[i] = s[tid] - v;
    if (tid == SCAN_B - 1) bsum[blockIdx.x] = s[tid];
}

__global__ void k_scan2(const int* __restrict__ bsum, int* __restrict__ bbase, int nb)
{
    __shared__ int s[128];
    int tid = threadIdx.x;
    int v = (tid < nb) ? bsum[tid] : 0;
    s[tid] = v; __syncthreads();
    for (int off = 1; off < 128; off <<= 1) {
        int t = (tid >= off) ? s[tid - off] : 0;
        __syncthreads();
        s[tid] += t;
        __syncthreads();
    }
    bbase[tid] = s[tid] - v;
}

__global__ void k_scan3(int* __restrict__ part, const int* __restrict__ bbase, int* __restrict__ cursor)
{
    int i = blockIdx.x * SCAN_B + threadIdx.x;
    if (i >= N_NODES) return;
    int o = part[i] + bbase[blockIdx.x];
    part[i] = o;
    cursor[i] = o;
}

// ============ CSR fill ============
__global__ void k_csr_fill(const int* __restrict__ ei, const float* __restrict__ edge_attr,
                           const int* __restrict__ types, int* __restrict__ cursor,
                           int* __restrict__ csr)
{
    int e = blockIdx.x * blockDim.x + threadIdx.x;
    if (e >= N_EDGES) return;
    int row = ei[e], col = ei[N_EDGES + e];
    int bt = (int)edge_attr[e * 4];
    bt = min(max(bt, 0), 4);
    int pos = atomicAdd(&cursor[row], 1);
    csr[pos] = col | (bt << 20) | (types[col] << 24);
}

// ============ layer-0 aggregation (tables) -> h in bf16 ============
__global__ __launch_bounds__(256) void k_agg0(const int* __restrict__ offsets, const int* __restrict__ degree,
                       const int* __restrict__ types,
                       const float* __restrict__ self0_tab, const float* __restrict__ msg0_tab,
                       const int* __restrict__ csr, u16* __restrict__ h)
{
    int wid = threadIdx.x >> 6, lane = threadIdx.x & 63;
    int node = blockIdx.x * 4 + wid;
    if (node >= N_NODES) return;
    int t = types[node];
    float4 acc = *(const float4*)&self0_tab[t * 256 + lane * 4];
    int start = offsets[node], deg = degree[node];
    for (int j = 0; j < deg; ++j) {
        int p = csr[start + j];
        int combo = ((p >> 24) & 0xF) * 5 + ((p >> 20) & 7);
        float4 m = *(const float4*)&msg0_tab[combo * 256 + lane * 4];
        acc.x += m.x; acc.y += m.y; acc.z += m.z; acc.w += m.w;
    }
    ushort4 r;
    r.x = f2bf(fmaxf(acc.x, 0.f)); r.y = f2bf(fmaxf(acc.y, 0.f));
    r.z = f2bf(fmaxf(acc.z, 0.f)); r.w = f2bf(fmaxf(acc.w, 0.f));
    *(ushort4*)&h[(size_t)node * 256 + lane * 4] = r;
}

// ============ layers 1,2 aggregation: h = relu(hs + sum relu(hm[col]+bondtab[bt])) ============
__global__ __launch_bounds__(256) void k_agg12(const int* __restrict__ offsets, const int* __restrict__ degree,
                        const u16* __restrict__ hs, const u16* __restrict__ hm,
                        const float* __restrict__ bondtab, const int* __restrict__ csr,
                        u16* __restrict__ h)
{
    int wid = threadIdx.x >> 6, lane = threadIdx.x & 63;
    int node = blockIdx.x * 4 + wid;
    if (node >= N_NODES) return;
    ushort4 s4 = *(const ushort4*)&hs[(size_t)node * 256 + lane * 4];
    float ax = bf2f(s4.x), ay = bf2f(s4.y), az = bf2f(s4.z), aw = bf2f(s4.w);
    int start = offsets[node], deg = degree[node];
    for (int j = 0; j < deg; ++j) {
        int p = csr[start + j];
        int c = p & 0xFFFFF;
        int bt = (p >> 20) & 7;
        ushort4 m4 = *(const ushort4*)&hm[(size_t)c * 256 + lane * 4];
        float4 bb = *(const float4*)&bondtab[bt * 256 + lane * 4];
        ax += fmaxf(bf2f(m4.x) + bb.x, 0.f);
        ay += fmaxf(bf2f(m4.y) + bb.y, 0.f);
        az += fmaxf(bf2f(m4.z) + bb.z, 0.f);
        aw += fmaxf(bf2f(m4.w) + bb.w, 0.f);
    }
    ushort4 r;
    r.x = f2bf(fmaxf(ax, 0.f)); r.y = f2bf(fmaxf(ay, 0.f));
    r.z = f2bf(fmaxf(az, 0.f)); r.w = f2bf(fmaxf(aw, 0.f));
    *(ushort4*)&h[(size_t)node * 256 + lane * 4] = r;
}

// ============ violations + damping: bf16 h -> fp32 h_out + bf16 damped h ============
__global__ void k_damp(const u16* __restrict__ h, const int* __restrict__ degree,
                       const int* __restrict__ pvarr,
                       float* __restrict__ h_out, u16* __restrict__ hd_bf,
                       float* __restrict__ viol_out)
{
    int idx = blockIdx.x * blockDim.x + threadIdx.x;
    if (idx >= N_NODES * 64) return;
    int i = idx >> 6, q = idx & 63;
    float viol = fmaxf((float)degree[i] - (float)pvarr[i], 0.f);
    float s = 1.f / (1.f + viol);
    ushort4 v4 = *(const ushort4*)&h[(size_t)i * 256 + q * 4];
    float4 v;
    v.x = bf2f(v4.x) * s; v.y = bf2f(v4.y) * s; v.z = bf2f(v4.z) * s; v.w = bf2f(v4.w) * s;
    *(float4*)&h_out[(size_t)i * 256 + q * 4] = v;
    ushort4 r;
    r.x = f2bf(v.x); r.y = f2bf(v.y); r.z = f2bf(v.z); r.w = f2bf(v.w);
    *(ushort4*)&hd_bf[(size_t)i * 256 + q * 4] = r;
    if (q == 0) viol_out[i] = viol;
}

// ================== bf16 MFMA GEMM core (128x128 tile, BK=32, K=256) ==================
// A: bf16 [M_PAD][256] row-major; Bt: bf16 [N][256] row-major (i.e. B^T).
// Stages via global_load_lds width-16; 16x16x32 MFMA; 4 waves each 64x64.

#define GLL(gp, lp) __builtin_amdgcn_global_load_lds( \
    (const __attribute__((address_space(1))) unsigned int*)(gp), \
    (__attribute__((address_space(3))) unsigned int*)(lp), 16, 0, 0)

// variant 1: dual bf16 outputs (layer GEMM, N=512): cols<256 -> Dm, cols>=256 -> Ds
__global__ __launch_bounds__(256) void k_gemm_bf16_dual(
    const u16* __restrict__ A, const u16* __restrict__ Bt,
    const float* __restrict__ bias512,
    u16* __restrict__ Dm, u16* __restrict__ Ds, int M)
{
    __shared__ u16 As[128 * 32];
    __shared__ u16 Bs[128 * 32];
    int t = threadIdx.x;
    int lane = t & 63, w = t >> 6;
    int wm = w & 1, wn = w >> 1;
    int bn = blockIdx.x * 128;
    int bm = blockIdx.y * 128;
    f32x4 zero = {0.f, 0.f, 0.f, 0.f};
    f32x4 acc[4][4];
    #pragma unroll
    for (int i = 0; i < 4; ++i)
        #pragma unroll
        for (int j = 0; j < 4; ++j) acc[i][j] = zero;

    int arow = t >> 2, acol = (t & 3) * 8;
    const u16* Ag = A + (size_t)(bm + arow) * 256 + acol;
    const u16* Bg = Bt + (size_t)(bn + arow) * 256 + acol;
    u16* Asp = As + t * 8;
    u16* Bsp = Bs + t * 8;
    int q = lane >> 4, r = lane & 15;

    for (int k0 = 0; k0 < 256; k0 += 32) {
        __syncthreads();
        GLL(Ag + k0,            Asp);
        GLL(Ag + 64 * 256 + k0, Asp + 2048);
        GLL(Bg + k0,            Bsp);
        GLL(Bg + 64 * 256 + k0, Bsp + 2048);
        __syncthreads();
        bf16x8 af[4], bfr[4];
        #pragma unroll
        for (int i = 0; i < 4; ++i)
            af[i] = *(const bf16x8*)&As[(wm * 64 + i * 16 + r) * 32 + q * 8];
        #pragma unroll
        for (int j = 0; j < 4; ++j)
            bfr[j] = *(const bf16x8*)&Bs[(wn * 64 + j * 16 + r) * 32 + q * 8];
        #pragma unroll
        for (int i = 0; i < 4; ++i)
            #pragma unroll
            for (int j = 0; j < 4; ++j)
                acc[i][j] = __builtin_amdgcn_mfma_f32_16x16x32_bf16(af[i], bfr[j], acc[i][j], 0, 0, 0);
    }
    #pragma unroll
    for (int i = 0; i < 4; ++i) {
        int rowb = bm + wm * 64 + i * 16 + q * 4;
        #pragma unroll
        for (int j = 0; j < 4; ++j) {
            int colg = bn + wn * 64 + j * 16 + r;
            float bv = bias512[colg];
            u16* D = (colg < 256) ? Dm : Ds;
            int col = colg & 255;
            #pragma unroll
            for (int rr = 0; rr < 4; ++rr) {
                int rowg = rowb + rr;
                if (rowg < M) D[(size_t)rowg * 256 + col] = f2bf(acc[i][j][rr] + bv);
            }
        }
    }
}

// variant 2: fp32 output, optional relu (N = 128 or 256, ldc = N)
__global__ __launch_bounds__(256) void k_gemm_bf16_f32out(
    const u16* __restrict__ A, const u16* __restrict__ Bt,
    const float* __restrict__ bias,
    float* __restrict__ C, int ldc, int M, int do_relu)
{
    __shared__ u16 As[128 * 32];
    __shared__ u16 Bs[128 * 32];
    int t = threadIdx.x;
    int lane = t & 63, w = t >> 6;
    int wm = w & 1, wn = w >> 1;
    int bn = blockIdx.x * 128;
    int bm = blockIdx.y * 128;
    f32x4 zero = {0.f, 0.f, 0.f, 0.f};
    f32x4 acc[4][4];
    #pragma unroll
    for (int i = 0; i < 4; ++i)
        #pragma unroll
        for (int j = 0; j < 4; ++j) acc[i][j] = zero;

    int arow = t >> 2, acol = (t & 3) * 8;
    const u16* Ag = A + (size_t)(bm + arow) * 256 + acol;
    const u16* Bg = Bt + (size_t)(bn + arow) * 256 + acol;
    u16* Asp = As + t * 8;
    u16* Bsp = Bs + t * 8;
    int q = lane >> 4, r = lane & 15;

    for (int k0 = 0; k0 < 256; k0 += 32) {
        __syncthreads();
        GLL(Ag + k0,            Asp);
        GLL(Ag + 64 * 256 + k0, Asp + 2048);
        GLL(Bg + k0,            Bsp);
        GLL(Bg + 64 * 256 + k0, Bsp + 2048);
        __syncthreads();
        bf16x8 af[4], bfr[4];
        #pragma unroll
        for (int i = 0; i < 4; ++i)
            af[i] = *(const bf16x8*)&As[(wm * 64 + i * 16 + r) * 32 + q * 8];
        #pragma unroll
        for (int j = 0; j < 4; ++j)
            bfr[j] = *(const bf16x8*)&Bs[(wn * 64 + j * 16 + r) * 32 + q * 8];
        #pragma unroll
        for (int i = 0; i < 4; ++i)
            #pragma unroll
            for (int j = 0; j < 4; ++j)
                acc[i][j] = __builtin_amdgcn_mfma_f32_16x16x32_bf16(af[i], bfr[j], acc[i][j], 0, 0, 0);
    }
    #pragma unroll
    for (int i = 0; i < 4; ++i) {
        int rowb = bm + wm * 64 + i * 16 + q * 4;
        #pragma unroll
        for (int j = 0; j < 4; ++j) {
            int colg = bn + wn * 64 + j * 16 + r;
            float bv = bias ? bias[colg] : 0.f;
            #pragma unroll
            for (int rr = 0; rr < 4; ++rr) {
                int rowg = rowb + rr;
                if (rowg < M) {
                    float vv = acc[i][j][rr] + bv;
                    if (do_relu) vv = fmaxf(vv, 0.f);
                    C[(size_t)rowg * ldc + colg] = vv;
                }
            }
        }
    }
}

// ============ generic fp32 tiled GEMM (kept for small tails) ============
#define BM 128
#define BN 64
#define BK 16
__global__ __launch_bounds__(256) void k_gemm(const float* __restrict__ A, int lda,
    const float* __restrict__ B, int ldb, const float* __restrict__ bias,
    float* __restrict__ C, int ldc, int M, int N, int K, int do_relu)
{
    __shared__ float As[BK][BM];
    __shared__ float Bs[BK][BN];
    int tid = threadIdx.x;
    int bm = blockIdx.x * BM, bn = blockIdx.y * BN;
    int tx = tid & 15, ty = tid >> 4;
    float acc[8][4];
    #pragma unroll
    for (int i = 0; i < 8; ++i)
        #pragma unroll
        for (int j = 0; j < 4; ++j) acc[i][j] = 0.f;

    int ar = tid >> 1;
    int ak = (tid & 1) * 8;
    int bk = tid >> 4;
    int bn4 = (tid & 15) * 4;

    for (int k0 = 0; k0 < K; k0 += BK) {
        float4 a0 = make_float4(0.f, 0.f, 0.f, 0.f), a1 = a0, b0 = a0;
        if (bm + ar < M) {
            const float* ap = A + (size_t)(bm + ar) * lda + k0 + ak;
            a0 = *(const float4*)ap;
            a1 = *(const float4*)(ap + 4);
        }
        if (bn + bn4 < N) {
            b0 = *(const float4*)(B + (size_t)(k0 + bk) * ldb + bn + bn4);
        }
        __syncthreads();
        As[ak + 0][ar] = a0.x; As[ak + 1][ar] = a0.y; As[ak + 2][ar] = a0.z; As[ak + 3][ar] = a0.w;
        As[ak + 4][ar] = a1.x; As[ak + 5][ar] = a1.y; As[ak + 6][ar] = a1.z; As[ak + 7][ar] = a1.w;
        *(float4*)&Bs[bk][bn4] = b0;
        __syncthreads();
        #pragma unroll
        for (int kk = 0; kk < BK; ++kk) {
            float4 av0 = *(const float4*)&As[kk][ty * 8];
            float4 av1 = *(const float4*)&As[kk][ty * 8 + 4];
            float4 bv  = *(const float4*)&Bs[kk][tx * 4];
            float a[8] = {av0.x, av0.y, av0.z, av0.w, av1.x, av1.y, av1.z, av1.w};
            float bb[4] = {bv.x, bv.y, bv.z, bv.w};
            #pragma unroll
            for (int i = 0; i < 8; ++i)
                #pragma unroll
                for (int j = 0; j < 4; ++j) acc[i][j] += a[i] * bb[j];
        }
    }
    if (bn + tx * 4 < N) {
        float4 bias4 = make_float4(0.f, 0.f, 0.f, 0.f);
        if (bias) bias4 = *(const float4*)&bias[bn + tx * 4];
        #pragma unroll
        for (int i = 0; i < 8; ++i) {
            int m = bm + ty * 8 + i;
            if (m < M) {
                float4 c;
                c.x = acc[i][0] + bias4.x; c.y = acc[i][1] + bias4.y;
                c.z = acc[i][2] + bias4.z; c.w = acc[i][3] + bias4.w;
                if (do_relu) {
                    c.x = fmaxf(c.x, 0.f); c.y = fmaxf(c.y, 0.f);
                    c.z = fmaxf(c.z, 0.f); c.w = fmaxf(c.w, 0.f);
                }
                *(float4*)&C[(size_t)m * ldc + bn + tx * 4] = c;
            }
        }
    }
}

// ============ bond t1: T1[e,128] = relu(u[row]+v[col]+pvr*w512+pvc*w513) ============
__global__ void k_bond_t1(const int* __restrict__ ei, const int* __restrict__ pvarr,
                          const float* __restrict__ uv,
                          const float* __restrict__ bc_w1, float* __restrict__ T1,
                          int e0, int ecnt)
{
    int idx = blockIdx.x * blockDim.x + threadIdx.x;
    if (idx >= ecnt * 32) return;
    int el = idx >> 5, q = idx & 31;
    int e = e0 + el;
    int row = ei[e], col = ei[N_EDGES + e];
    float pvr = (float)pvarr[row], pvc = (float)pvarr[col];
    float4 uu = *(const float4*)&uv[(size_t)row * 256 + q * 4];
    float4 vv = *(const float4*)&uv[(size_t)col * 256 + 128 + q * 4];
    float4 w5 = *(const float4*)&bc_w1[512 * 128 + q * 4];
    float4 w6 = *(const float4*)&bc_w1[513 * 128 + q * 4];
    float4 t;
    t.x = fmaxf(uu.x + vv.x + pvr * w5.x + pvc * w6.x, 0.f);
    t.y = fmaxf(uu.y + vv.y + pvr * w5.y + pvc * w6.y, 0.f);
    t.z = fmaxf(uu.z + vv.z + pvr * w5.z + pvc * w6.z, 0.f);
    t.w = fmaxf(uu.w + vv.w + pvr * w5.w + pvc * w6.w, 0.f);
    *(float4*)&T1[(size_t)el * 128 + q * 4] = t;
}

// ============ bond out ============
__global__ __launch_bounds__(256) void k_bond_out(const float* __restrict__ T2, const int* __restrict__ ei,
                           const int* __restrict__ types, const int* __restrict__ pvarr,
                           const float* __restrict__ bc_w3, const float* __restrict__ bc_b3,
                           float* __restrict__ bl_out, int e0, int ecnt)
{
    __shared__ float W3s[256];
    __shared__ float b3s[4];
    int tid = threadIdx.x;
    W3s[tid] = bc_w3[tid];
    if (tid < 4) b3s[tid] = bc_b3[tid];
    __syncthreads();
    int el = blockIdx.x * blockDim.x + tid;
    if (el >= ecnt) return;
    int e = e0 + el;
    const float* t2 = T2 + (size_t)el * 64;
    float a0 = b3s[0], a1 = b3s[1], a2 = b3s[2], a3 = b3s[3];
    for (int k = 0; k < 64; k += 4) {
        float4 t = *(const float4*)&t2[k];
        a0 += t.x * W3s[(k + 0) * 4 + 0]; a1 += t.x * W3s[(k + 0) * 4 + 1];
        a2 += t.x * W3s[(k + 0) * 4 + 2]; a3 += t.x * W3s[(k + 0) * 4 + 3];
        a0 += t.y * W3s[(k + 1) * 4 + 0]; a1 += t.y * W3s[(k + 1) * 4 + 1];
        a2 += t.y * W3s[(k + 1) * 4 + 2]; a3 += t.y * W3s[(k + 1) * 4 + 3];
        a0 += t.z * W3s[(k + 2) * 4 + 0]; a1 += t.z * W3s[(k + 2) * 4 + 1];
        a2 += t.z * W3s[(k + 2) * 4 + 2]; a3 += t.z * W3s[(k + 2) * 4 + 3];
        a0 += t.w * W3s[(k + 3) * 4 + 0]; a1 += t.w * W3s[(k + 3) * 4 + 1];
        a2 += t.w * W3s[(k + 3) * 4 + 2]; a3 += t.w * W3s[(k + 3) * 4 + 3];
    }
    int row = ei[e], col = ei[N_EDGES + e];
    int tr = types[row], tc = types[col];
    int pr = pvarr[row], pc = pvarr[col];
    float halogen = (tr == 4 || tr == 5 || tc == 4 || tc == 5) ? 1.f : 0.f;
    float l1 = (pr <= 1 || pc <= 1) ? 1.f : 0.f;
    float l2 = (pr <= 2 || pc <= 2) ? 1.f : 0.f;
    float pen13 = -100.f * halogen - 50.f * l1;
    a1 += pen13;
    a3 += pen13;
    a2 += pen13 - 50.f * l2;
    float4 o = make_float4(a0, a1, a2, a3);
    *(float4*)&bl_out[(size_t)e * 4] = o;
}

// ================================================================
extern "C" void kernel_launch(void* const* d_in, const int* in_sizes, int n_in,
                              void* d_out, int out_size, void* d_ws, size_t ws_size,
                              hipStream_t stream)
{
    const float* x          = (const float*)d_in[0];
    const float* edge_attr  = (const float*)d_in[1];
    const float* atom_emb   = (const float*)d_in[2];
    const float* bond_emb   = (const float*)d_in[3];
    const float* vp_w1      = (const float*)d_in[4];
    const float* vp_b1      = (const float*)d_in[5];
    const float* vp_w2      = (const float*)d_in[6];
    const float* vp_b2      = (const float*)d_in[7];
    const float* gnn_wself  = (const float*)d_in[8];
    const float* gnn_bself  = (const float*)d_in[9];
    const float* gnn_wmsg   = (const float*)d_in[10];
    const float* gnn_bmsg   = (const float*)d_in[11];
    const float* bc_w1      = (const float*)d_in[12];
    const float* bc_b1      = (const float*)d_in[13];
    const float* bc_w2      = (const float*)d_in[14];
    const float* bc_b2      = (const float*)d_in[15];
    const float* bc_w3      = (const float*)d_in[16];
    const float* bc_b3      = (const float*)d_in[17];
    const float* cp_w1      = (const float*)d_in[18];
    const float* cp_b1      = (const float*)d_in[19];
    const float* cp_w2      = (const float*)d_in[20];
    const float* cp_b2      = (const float*)d_in[21];
    const int*   ei         = (const int*)d_in[22];

    float* out    = (float*)d_out;
    float* h_out  = out + H_OFF;
    float* cp_out = out + CP_OFF;
    float* vl_out = out + VL_OFF;
    float* bl_out = out + BL_OFF;
    float* vi_out = out + VI_OFF;

    // ---- workspace layout (bytes) ----
    char* base = (char*)d_ws;
    const size_t BF_SZ = (size_t)M_PAD * 256 * 2;          // 51,249,152
    u16*   hs_bf   = (u16*)(base + 0);                     // region 0 (also t1cp / T1+T2 later)
    float* t1cp    = (float*)(base + 0);                   // [M][128] f32, after layers
    float* T1      = (float*)(base + 0);                   // chunk [50000][128]
    float* T2      = (float*)(base + 25600000);            // chunk [50000][64]
    u16*   hd_bf   = (u16*)(base + BF_SZ);                 // damped h bf16
    u16*   h_bf    = (u16*)(base + 2 * BF_SZ);             // h bf16
    float* uv      = (float*)(base + 2 * BF_SZ);           // [M][256] f32 (reuses h_bf+hm_bf)
    u16*   hm_bf   = (u16*)(base + 3 * BF_SZ);             // hm bf16
    char*  w       = base + 4 * BF_SZ;
    int* degree  = (int*)w; w += (size_t)N_NODES * 4;
    int* offsets = (int*)w; w += (size_t)N_NODES * 4;
    int* cursor  = (int*)w; w += (size_t)N_NODES * 4;
    int* types   = (int*)w; w += (size_t)N_NODES * 4;
    int* pvarr   = (int*)w; w += (size_t)N_NODES * 4;
    int* csr     = (int*)w; w += (size_t)N_EDGES * 4;
    int* bsum    = (int*)w; w += 4096;
    int* bbase   = (int*)w; w += 4096;
    int* pv_tab  = (int*)w; w += 1024;
    float* vl_tab    = (float*)w; w += 2048;
    float* h0_tab    = (float*)w; w += 11 * 256 * 4;
    float* self0_tab = (float*)w; w += 11 * 256 * 4;
    float* msg0_tab  = (float*)w; w += 55 * 256 * 4;
    float* bondtab   = (float*)w; w += 2 * 5 * 256 * 4;
    u16* BtL1 = (u16*)w; w += 512 * 256 * 2;
    u16* BtL2 = (u16*)w; w += 512 * 256 * 2;
    u16* BtUV = (u16*)w; w += 256 * 256 * 2;
    u16* BtCP = (u16*)w; w += 128 * 256 * 2;
    float* bias512 = (float*)w; w += 2 * 512 * 4;
    float* biasUV  = (float*)w; w += 256 * 4;

    // ---- setup ----
    k_type_mlp<<<1, 256, 0, stream>>>(atom_emb, vp_w1, vp_b1, vp_w2, vp_b2, pv_tab, vl_tab, h0_tab);
    k_tables<<<76, 256, 0, stream>>>(bond_emb, gnn_wself, gnn_bself, gnn_wmsg, gnn_bmsg,
                                     h0_tab, self0_tab, msg0_tab, bondtab);
    k_wtrans<<<1408, 256, 0, stream>>>(gnn_wmsg, gnn_wself, bc_w1, cp_w1, BtL1, BtL2, BtUV, BtCP);
    k_setup_bias<<<5, 256, 0, stream>>>(gnn_bself, bc_b1, bias512, biasUV);
    k_node_init<<<(N_NODES + 255) / 256, 256, 0, stream>>>(x, pv_tab, vl_tab, types, pvarr, degree, vl_out);
    k_edge_deg<<<(N_EDGES + 255) / 256, 256, 0, stream>>>(ei, degree);
    int nb = (N_NODES + SCAN_B - 1) / SCAN_B;
    k_scan1<<<nb, SCAN_B, 0, stream>>>(degree, offsets, bsum);
    k_scan2<<<1, 128, 0, stream>>>(bsum, bbase, nb);
    k_scan3<<<nb, SCAN_B, 0, stream>>>(offsets, bbase, cursor);
    k_csr_fill<<<(N_EDGES + 255) / 256, 256, 0, stream>>>(ei, edge_attr, types, cursor, csr);
    k_agg0<<<N_NODES / 4, 256, 0, stream>>>(offsets, degree, types, self0_tab, msg0_tab, csr, h_bf);

    // ---- GNN layers 1,2 (bf16 MFMA) ----
    const int MT = (N_NODES + 127) / 128;  // 782
    for (int l = 1; l <= 2; ++l) {
        const u16* BtL = (l == 1) ? BtL1 : BtL2;
        dim3 g(4, MT);
        k_gemm_bf16_dual<<<g, 256, 0, stream>>>(h_bf, BtL, bias512 + (size_t)(l - 1) * 512,
                                                hm_bf, hs_bf, N_NODES);
        k_agg12<<<N_NODES / 4, 256, 0, stream>>>(offsets, degree, hs_bf, hm_bf,
                                                 bondtab + (size_t)(l - 1) * 5 * 256, csr, h_bf);
    }

    // ---- damp ----
    k_damp<<<(N_NODES * 64 + 255) / 256, 256, 0, stream>>>(h_bf, degree, pvarr, h_out, hd_bf, vi_out);

    // ---- u|v and chem-props (bf16 MFMA) ----
    {
        dim3 g(2, MT);
        k_gemm_bf16_f32out<<<g, 256, 0, stream>>>(hd_bf, BtUV, biasUV, uv, 256, N_NODES, 0);
        dim3 g1(1, MT);
        k_gemm_bf16_f32out<<<g1, 256, 0, stream>>>(hd_bf, BtCP, cp_b1, t1cp, 128, N_NODES, 1);
        // cp2 (fp32 tail) — must run before bond chunks reuse region 0
        dim3 g2((N_NODES + BM - 1) / BM, 1);
        k_gemm<<<g2, 256, 0, stream>>>(t1cp, 128, cp_w2, 32, cp_b2, cp_out, 32, N_NODES, 32, 128, 0);
    }

    // ---- bond prediction in 6 chunks of 50000 ----
    const int ECH = 50000;
    for (int c = 0; c < 6; ++c) {
        int e0 = c * ECH;
        k_bond_t1<<<(ECH * 32 + 255) / 256, 256, 0, stream>>>(ei, pvarr, uv, bc_w1, T1, e0, ECH);
        dim3 g2((ECH + BM - 1) / BM, 1);
        k_gemm<<<g2, 256, 0, stream>>>(T1, 128, bc_w2, 64, bc_b2, T2, 64, ECH, 64, 128, 1);
        k_bond_out<<<(ECH + 255) / 256, 256, 0, stream>>>(T2, ei, types, pvarr, bc_w3, bc_b3, bl_out, e0, ECH);
    }
}

// Round 3
// 834.203 us; speedup vs baseline: 2.1131x; 1.1142x over previous
//
#include <hip/hip_runtime.h>

#define N_NODES 100000
#define N_EDGES 300000
#define M_PAD   100096   // 782*128
#define E_PAD   300032   // 2344*128

typedef unsigned short u16;
typedef short bf16x8 __attribute__((ext_vector_type(8)));
typedef float f32x4  __attribute__((ext_vector_type(4)));

__device__ __forceinline__ float bf2f(u16 u) {
    unsigned x = ((unsigned)u) << 16;
    return __builtin_bit_cast(float, x);
}
__device__ __forceinline__ u16 f2bf(float f) {
    unsigned u = __builtin_bit_cast(unsigned, f);
    unsigned r = (u + 0x7FFF + ((u >> 16) & 1)) >> 16;
    return (u16)r;
}

// ---------------- output layout (floats) ----------------
#define H_OFF   0
#define CP_OFF  25600000
#define VL_OFF  28800000
#define BL_OFF  29600000
#define VI_OFF  30800000

#define GLL(gp, lp) __builtin_amdgcn_global_load_lds( \
    (const __attribute__((address_space(1))) unsigned int*)(gp), \
    (__attribute__((address_space(3))) unsigned int*)(lp), 16, 0, 0)

// ============ per-atom-type valence MLP + h0 rows ============
__global__ void k_type_mlp(const float* __restrict__ atom_emb,
                           const float* __restrict__ vp_w1, const float* __restrict__ vp_b1,
                           const float* __restrict__ vp_w2, const float* __restrict__ vp_b2,
                           int* __restrict__ pv_tab, float* __restrict__ vl_tab,
                           float* __restrict__ h0_tab)
{
    int tid = threadIdx.x;
    for (int i = tid; i < 11 * 256; i += 256) h0_tab[i] = 0.f;
    __syncthreads();
    if (tid < 11) {
        int t = tid;
        const float* ae = atom_emb + t * 64;
        float lg[8];
        #pragma unroll
        for (int c = 0; c < 8; ++c) lg[c] = vp_b2[c];
        for (int j = 0; j < 32; ++j) {
            float z = vp_b1[j];
            for (int d = 0; d < 64; ++d) z += ae[d] * vp_w1[d * 32 + j];
            z = fmaxf(z, 0.f);
            #pragma unroll
            for (int c = 0; c < 8; ++c) lg[c] += z * vp_w2[j * 8 + c];
        }
        int best = 0;
        #pragma unroll
        for (int c = 1; c < 8; ++c) if (lg[c] > lg[best]) best = c;
        pv_tab[t] = best + 1;
        for (int c = 0; c < 8; ++c) vl_tab[t * 8 + c] = lg[c];
        float* h0 = h0_tab + t * 256;
        for (int d = 0; d < 64; ++d) h0[d] = ae[d];
        h0[64 + best] = 1.f;
    }
}

// ============ layer-0 tables + bond tables for layers 1,2 ============
__global__ void k_tables(const float* __restrict__ bond_emb,
                         const float* __restrict__ gnn_wself, const float* __restrict__ gnn_bself,
                         const float* __restrict__ gnn_wmsg, const float* __restrict__ gnn_bmsg,
                         const float* __restrict__ h0_tab,
                         float* __restrict__ self0_tab, float* __restrict__ msg0_tab,
                         float* __restrict__ bondtab)
{
    int b = blockIdx.x, c = threadIdx.x;
    if (b < 11) {
        int t = b;
        const float* h0 = h0_tab + t * 256;
        float acc = gnn_bself[c];
        for (int k = 0; k < 256; ++k) acc += h0[k] * gnn_wself[k * 256 + c];
        self0_tab[t * 256 + c] = acc;
    } else if (b < 66) {
        int idx = b - 11; int t = idx / 5, bb = idx % 5;
        const float* h0 = h0_tab + t * 256;
        float acc = gnn_bmsg[c];
        for (int k = 0; k < 256; ++k) acc += h0[k] * gnn_wmsg[k * 256 + c];
        const float* be = bond_emb + bb * 64;
        for (int k = 0; k < 64; ++k) acc += be[k] * gnn_wmsg[(256 + k) * 256 + c];
        msg0_tab[idx * 256 + c] = fmaxf(acc, 0.f);
    } else {
        int idx = b - 66; int l = idx / 5 + 1, bb = idx % 5;
        const float* w = gnn_wmsg + (size_t)l * 320 * 256;
        const float* be = bond_emb + bb * 64;
        float acc = gnn_bmsg[l * 256 + c];
        for (int k = 0; k < 64; ++k) acc += be[k] * w[(256 + k) * 256 + c];
        bondtab[(l - 1) * 5 * 256 + bb * 256 + c] = acc;
    }
}

// ============ bf16-transposed weight tables ============
// BtL1/BtL2: [512][256] (rows 0..255 Wmsg_top^T, 256..511 Wself^T)
// Bt3: [384][256] (rows 0..127 u-part bc_w1^T, 128..255 v-part, 256..383 cp_w1^T)
// BtW2: [128][128] (bc_w2^T, rows>=64 zero) ; BtCP2: [128][128] (cp_w2^T, rows>=32 zero)
__global__ void k_wtrans(const float* __restrict__ wmsg, const float* __restrict__ wself,
                         const float* __restrict__ bcw1, const float* __restrict__ cpw1,
                         const float* __restrict__ bcw2, const float* __restrict__ cpw2,
                         u16* __restrict__ BtL1, u16* __restrict__ BtL2, u16* __restrict__ Bt3,
                         u16* __restrict__ BtW2, u16* __restrict__ BtCP2)
{
    int b = blockIdx.x, k = threadIdx.x;
    if (b < 512) {
        int n = b;
        float v = (n < 256) ? wmsg[(size_t)1 * 320 * 256 + (size_t)k * 256 + n]
                            : wself[(size_t)1 * 256 * 256 + (size_t)k * 256 + (n - 256)];
        BtL1[n * 256 + k] = f2bf(v);
    } else if (b < 1024) {
        int n = b - 512;
        float v = (n < 256) ? wmsg[(size_t)2 * 320 * 256 + (size_t)k * 256 + n]
                            : wself[(size_t)2 * 256 * 256 + (size_t)k * 256 + (n - 256)];
        BtL2[n * 256 + k] = f2bf(v);
    } else if (b < 1408) {
        int n = b - 1024;
        float v;
        if (n < 128)      v = bcw1[k * 128 + n];
        else if (n < 256) v = bcw1[(256 + k) * 128 + (n - 128)];
        else              v = cpw1[k * 128 + (n - 256)];
        Bt3[n * 256 + k] = f2bf(v);
    } else if (b < 1536) {
        int n = b - 1408;
        if (k < 128) BtW2[n * 128 + k] = f2bf(n < 64 ? bcw2[k * 64 + n] : 0.f);
    } else {
        int n = b - 1536;
        if (k < 128) BtCP2[n * 128 + k] = f2bf(n < 32 ? cpw2[k * 32 + n] : 0.f);
    }
}

// bias512[l][c]: 0 for c<256 (bmsg folded into bondtab), bself for c>=256
// biasPost[384] = [bc_b1(128) | 0(128) | cp_b1(128)]
__global__ void k_setup_bias(const float* __restrict__ bself, const float* __restrict__ bcb1,
                             const float* __restrict__ cpb1,
                             float* __restrict__ bias512, float* __restrict__ biasPost)
{
    int i = blockIdx.x * 256 + threadIdx.x;
    if (i < 1024) {
        int l = i >> 9, c = i & 511;
        bias512[l * 512 + c] = (c < 256) ? 0.f : bself[(l + 1) * 256 + (c - 256)];
    } else if (i < 1408) {
        int c = i - 1024;
        biasPost[c] = (c < 128) ? bcb1[c] : ((c < 256) ? 0.f : cpb1[c - 256]);
    }
}

// ============ node init ============
__global__ void k_node_init(const float* __restrict__ x, const int* __restrict__ pv_tab,
                            const float* __restrict__ vl_tab,
                            int* __restrict__ types, int* __restrict__ pvarr,
                            int* __restrict__ degree, float* __restrict__ vl_out)
{
    int i = blockIdx.x * blockDim.x + threadIdx.x;
    if (i >= N_NODES) return;
    int t = (int)x[i * 16];
    t = min(max(t, 0), 10);
    types[i] = t;
    pvarr[i] = pv_tab[t];
    degree[i] = 0;
    float4 v0 = *(const float4*)&vl_tab[t * 8];
    float4 v1 = *(const float4*)&vl_tab[t * 8 + 4];
    *(float4*)&vl_out[i * 8]     = v0;
    *(float4*)&vl_out[i * 8 + 4] = v1;
}

__global__ void k_edge_deg(const int* __restrict__ ei, int* __restrict__ degree)
{
    int e = blockIdx.x * blockDim.x + threadIdx.x;
    if (e >= N_EDGES) return;
    atomicAdd(&degree[ei[e]], 1);
}

// ============ scan ============
#define SCAN_B 1024
__global__ void k_scan1(const int* __restrict__ degree, int* __restrict__ part, int* __restrict__ bsum)
{
    __shared__ int s[SCAN_B];
    int tid = threadIdx.x;
    int i = blockIdx.x * SCAN_B + tid;
    int v = (i < N_NODES) ? degree[i] : 0;
    s[tid] = v; __syncthreads();
    for (int off = 1; off < SCAN_B; off <<= 1) {
        int t = (tid >= off) ? s[tid - off] : 0;
        __syncthreads();
        s[tid] += t;
        __syncthreads();
    }
    if (i < N_NODES) part[i] = s[tid] - v;
    if (tid == SCAN_B - 1) bsum[blockIdx.x] = s[tid];
}

__global__ void k_scan2(const int* __restrict__ bsum, int* __restrict__ bbase, int nb)
{
    __shared__ int s[128];
    int tid = threadIdx.x;
    int v = (tid < nb) ? bsum[tid] : 0;
    s[tid] = v; __syncthreads();
    for (int off = 1; off < 128; off <<= 1) {
        int t = (tid >= off) ? s[tid - off] : 0;
        __syncthreads();
        s[tid] += t;
        __syncthreads();
    }
    bbase[tid] = s[tid] - v;
}

__global__ void k_scan3(int* __restrict__ part, const int* __restrict__ bbase, int* __restrict__ cursor)
{
    int i = blockIdx.x * SCAN_B + threadIdx.x;
    if (i >= N_NODES) return;
    int o = part[i] + bbase[blockIdx.x];
    part[i] = o;
    cursor[i] = o;
}

// ============ CSR fill ============
__global__ void k_csr_fill(const int* __restrict__ ei, const float* __restrict__ edge_attr,
                           const int* __restrict__ types, int* __restrict__ cursor,
                           int* __restrict__ csr)
{
    int e = blockIdx.x * blockDim.x + threadIdx.x;
    if (e >= N_EDGES) return;
    int row = ei[e], col = ei[N_EDGES + e];
    int bt = (int)edge_attr[e * 4];
    bt = min(max(bt, 0), 4);
    int pos = atomicAdd(&cursor[row], 1);
    csr[pos] = col | (bt << 20) | (types[col] << 24);
}

// ============ layer-0 aggregation (tables) -> h bf16 ============
__global__ __launch_bounds__(256) void k_agg0(const int* __restrict__ offsets, const int* __restrict__ degree,
                       const int* __restrict__ types,
                       const float* __restrict__ self0_tab, const float* __restrict__ msg0_tab,
                       const int* __restrict__ csr, u16* __restrict__ h)
{
    int wid = threadIdx.x >> 6, lane = threadIdx.x & 63;
    int node = blockIdx.x * 4 + wid;
    if (node >= N_NODES) return;
    int t = types[node];
    float4 acc = *(const float4*)&self0_tab[t * 256 + lane * 4];
    int start = offsets[node], deg = degree[node];
    for (int j = 0; j < deg; ++j) {
        int p = csr[start + j];
        int combo = ((p >> 24) & 0xF) * 5 + ((p >> 20) & 7);
        float4 m = *(const float4*)&msg0_tab[combo * 256 + lane * 4];
        acc.x += m.x; acc.y += m.y; acc.z += m.z; acc.w += m.w;
    }
    ushort4 r;
    r.x = f2bf(fmaxf(acc.x, 0.f)); r.y = f2bf(fmaxf(acc.y, 0.f));
    r.z = f2bf(fmaxf(acc.z, 0.f)); r.w = f2bf(fmaxf(acc.w, 0.f));
    *(ushort4*)&h[(size_t)node * 256 + lane * 4] = r;
}

// ============ layers 1,2 aggregation ============
__global__ __launch_bounds__(256) void k_agg12(const int* __restrict__ offsets, const int* __restrict__ degree,
                        const u16* __restrict__ hs, const u16* __restrict__ hm,
                        const float* __restrict__ bondtab, const int* __restrict__ csr,
                        u16* __restrict__ h)
{
    int wid = threadIdx.x >> 6, lane = threadIdx.x & 63;
    int node = blockIdx.x * 4 + wid;
    if (node >= N_NODES) return;
    ushort4 s4 = *(const ushort4*)&hs[(size_t)node * 256 + lane * 4];
    float ax = bf2f(s4.x), ay = bf2f(s4.y), az = bf2f(s4.z), aw = bf2f(s4.w);
    int start = offsets[node], deg = degree[node];
    for (int j = 0; j < deg; ++j) {
        int p = csr[start + j];
        int c = p & 0xFFFFF;
        int bt = (p >> 20) & 7;
        ushort4 m4 = *(const ushort4*)&hm[(size_t)c * 256 + lane * 4];
        float4 bb = *(const float4*)&bondtab[bt * 256 + lane * 4];
        ax += fmaxf(bf2f(m4.x) + bb.x, 0.f);
        ay += fmaxf(bf2f(m4.y) + bb.y, 0.f);
        az += fmaxf(bf2f(m4.z) + bb.z, 0.f);
        aw += fmaxf(bf2f(m4.w) + bb.w, 0.f);
    }
    ushort4 r;
    r.x = f2bf(fmaxf(ax, 0.f)); r.y = f2bf(fmaxf(ay, 0.f));
    r.z = f2bf(fmaxf(az, 0.f)); r.w = f2bf(fmaxf(aw, 0.f));
    *(ushort4*)&h[(size_t)node * 256 + lane * 4] = r;
}

// ============ violations + damping ============
__global__ void k_damp(const u16* __restrict__ h, const int* __restrict__ degree,
                       const int* __restrict__ pvarr,
                       float* __restrict__ h_out, u16* __restrict__ hd_bf,
                       float* __restrict__ viol_out)
{
    int idx = blockIdx.x * blockDim.x + threadIdx.x;
    if (idx >= N_NODES * 64) return;
    int i = idx >> 6, q = idx & 63;
    float viol = fmaxf((float)degree[i] - (float)pvarr[i], 0.f);
    float s = 1.f / (1.f + viol);
    ushort4 v4 = *(const ushort4*)&h[(size_t)i * 256 + q * 4];
    float4 v;
    v.x = bf2f(v4.x) * s; v.y = bf2f(v4.y) * s; v.z = bf2f(v4.z) * s; v.w = bf2f(v4.w) * s;
    *(float4*)&h_out[(size_t)i * 256 + q * 4] = v;
    ushort4 r;
    r.x = f2bf(v.x); r.y = f2bf(v.y); r.z = f2bf(v.z); r.w = f2bf(v.w);
    *(ushort4*)&hd_bf[(size_t)i * 256 + q * 4] = r;
    if (q == 0) viol_out[i] = viol;
}

// ================== A-resident layer GEMM: K=256, N=512 (4 N-tiles looped) ==================
// A [M_PAD][256] bf16; Bt [512][256] bf16. A staged ONCE in LDS (64 KB),
// B streamed double-buffered (2x8 KB), one barrier/iter with prefetch overlap.
__global__ __launch_bounds__(256) void k_gemm_layer(
    const u16* __restrict__ A, const u16* __restrict__ Bt,
    const float* __restrict__ bias512,
    u16* __restrict__ Dm, u16* __restrict__ Ds, int M)
{
    __shared__ u16 smem[40960];              // 80 KB: As 64 KB + 2x8 KB B
    u16* As  = smem;                          // 8 chunks x [128][32]
    u16* Bs0 = smem + 32768;
    u16* Bs1 = smem + 32768 + 4096;
    int t = threadIdx.x;
    int lane = t & 63, w = t >> 6;
    int wm = w & 1, wn = w >> 1;
    int bm = blockIdx.x * 128;
    int arow = t >> 2, acol = (t & 3) * 8;
    int q = lane >> 4, r = lane & 15;

    const u16* Ag = A + (size_t)(bm + arow) * 256 + acol;
    #pragma unroll
    for (int c = 0; c < 8; ++c) {
        GLL(Ag + c * 32,            As + c * 4096 + t * 8);
        GLL(Ag + 64 * 256 + c * 32, As + c * 4096 + 2048 + t * 8);
    }
    const u16* Bgbase = Bt + (size_t)arow * 256 + acol;
    GLL(Bgbase,            Bs0 + t * 8);
    GLL(Bgbase + 64 * 256, Bs0 + 2048 + t * 8);

    for (int nt = 0; nt < 4; ++nt) {
        f32x4 zero = {0.f, 0.f, 0.f, 0.f};
        f32x4 acc[4][4];
        #pragma unroll
        for (int i = 0; i < 4; ++i)
            #pragma unroll
            for (int j = 0; j < 4; ++j) acc[i][j] = zero;
        for (int kc = 0; kc < 8; ++kc) {
            int it = nt * 8 + kc;
            u16* cur = (it & 1) ? Bs1 : Bs0;
            u16* nxt = (it & 1) ? Bs0 : Bs1;
            __syncthreads();
            if (it < 31) {
                int nit = it + 1;
                const u16* Bg = Bgbase + (size_t)(nit >> 3) * 128 * 256 + (nit & 7) * 32;
                GLL(Bg,            nxt + t * 8);
                GLL(Bg + 64 * 256, nxt + 2048 + t * 8);
            }
            bf16x8 af[4], bfr[4];
            #pragma unroll
            for (int i = 0; i < 4; ++i)
                af[i] = *(const bf16x8*)&As[kc * 4096 + (wm * 64 + i * 16 + r) * 32 + q * 8];
            #pragma unroll
            for (int j = 0; j < 4; ++j)
                bfr[j] = *(const bf16x8*)&cur[(wn * 64 + j * 16 + r) * 32 + q * 8];
            #pragma unroll
            for (int i = 0; i < 4; ++i)
                #pragma unroll
                for (int j = 0; j < 4; ++j)
                    acc[i][j] = __builtin_amdgcn_mfma_f32_16x16x32_bf16(af[i], bfr[j], acc[i][j], 0, 0, 0);
        }
        #pragma unroll
        for (int i = 0; i < 4; ++i) {
            int rowb = bm + wm * 64 + i * 16 + q * 4;
            #pragma unroll
            for (int j = 0; j < 4; ++j) {
                int colg = nt * 128 + wn * 64 + j * 16 + r;
                float bv = bias512[colg];
                u16* D = (colg < 256) ? Dm : Ds;
                int col = colg & 255;
                #pragma unroll
                for (int rr = 0; rr < 4; ++rr) {
                    int rowg = rowb + rr;
                    if (rowg < M) D[(size_t)rowg * 256 + col] = f2bf(acc[i][j][rr] + bv);
                }
            }
        }
    }
}

// ================== A-resident post GEMM over hd: N=384 (uv 256 + cp1 128) ==================
__global__ __launch_bounds__(256) void k_gemm_post3(
    const u16* __restrict__ A, const u16* __restrict__ Bt3,
    const float* __restrict__ biasPost,
    u16* __restrict__ UV, u16* __restrict__ CP1, int M)
{
    __shared__ u16 smem[40960];
    u16* As  = smem;
    u16* Bs0 = smem + 32768;
    u16* Bs1 = smem + 32768 + 4096;
    int t = threadIdx.x;
    int lane = t & 63, w = t >> 6;
    int wm = w & 1, wn = w >> 1;
    int bm = blockIdx.x * 128;
    int arow = t >> 2, acol = (t & 3) * 8;
    int q = lane >> 4, r = lane & 15;

    const u16* Ag = A + (size_t)(bm + arow) * 256 + acol;
    #pragma unroll
    for (int c = 0; c < 8; ++c) {
        GLL(Ag + c * 32,            As + c * 4096 + t * 8);
        GLL(Ag + 64 * 256 + c * 32, As + c * 4096 + 2048 + t * 8);
    }
    const u16* Bgbase = Bt3 + (size_t)arow * 256 + acol;
    GLL(Bgbase,            Bs0 + t * 8);
    GLL(Bgbase + 64 * 256, Bs0 + 2048 + t * 8);

    for (int nt = 0; nt < 3; ++nt) {
        f32x4 zero = {0.f, 0.f, 0.f, 0.f};
        f32x4 acc[4][4];
        #pragma unroll
        for (int i = 0; i < 4; ++i)
            #pragma unroll
            for (int j = 0; j < 4; ++j) acc[i][j] = zero;
        for (int kc = 0; kc < 8; ++kc) {
            int it = nt * 8 + kc;
            u16* cur = (it & 1) ? Bs1 : Bs0;
            u16* nxt = (it & 1) ? Bs0 : Bs1;
            __syncthreads();
            if (it < 23) {
                int nit = it + 1;
                const u16* Bg = Bgbase + (size_t)(nit >> 3) * 128 * 256 + (nit & 7) * 32;
                GLL(Bg,            nxt + t * 8);
                GLL(Bg + 64 * 256, nxt + 2048 + t * 8);
            }
            bf16x8 af[4], bfr[4];
            #pragma unroll
            for (int i = 0; i < 4; ++i)
                af[i] = *(const bf16x8*)&As[kc * 4096 + (wm * 64 + i * 16 + r) * 32 + q * 8];
            #pragma unroll
            for (int j = 0; j < 4; ++j)
                bfr[j] = *(const bf16x8*)&cur[(wn * 64 + j * 16 + r) * 32 + q * 8];
            #pragma unroll
            for (int i = 0; i < 4; ++i)
                #pragma unroll
                for (int j = 0; j < 4; ++j)
                    acc[i][j] = __builtin_amdgcn_mfma_f32_16x16x32_bf16(af[i], bfr[j], acc[i][j], 0, 0, 0);
        }
        #pragma unroll
        for (int i = 0; i < 4; ++i) {
            int rowb = bm + wm * 64 + i * 16 + q * 4;
            #pragma unroll
            for (int j = 0; j < 4; ++j) {
                int coll = wn * 64 + j * 16 + r;
                float bv = biasPost[nt * 128 + coll];
                #pragma unroll
                for (int rr = 0; rr < 4; ++rr) {
                    int rowg = rowb + rr;
                    if (rowg < M) {
                        float val = acc[i][j][rr] + bv;
                        if (nt < 2) UV[(size_t)rowg * 256 + nt * 128 + coll] = f2bf(val);
                        else        CP1[(size_t)rowg * 128 + coll] = f2bf(fmaxf(val, 0.f));
                    }
                }
            }
        }
    }
}

// ================== small K=128 MFMA GEMM (tile 128x128, N<=128) ==================
// flags: bit0 = relu, bit1 = bf16 out
__global__ __launch_bounds__(256) void k_gemm_k128(
    const u16* __restrict__ A, const u16* __restrict__ Bt,
    const float* __restrict__ bias, void* __restrict__ Dv,
    int ldc, int M, int N, int flags)
{
    __shared__ u16 As[4096];
    __shared__ u16 Bs[4096];
    int t = threadIdx.x;
    int lane = t & 63, w = t >> 6;
    int wm = w & 1, wn = w >> 1;
    int bm = blockIdx.x * 128;
    int arow = t >> 2, acol = (t & 3) * 8;
    int q = lane >> 4, r = lane & 15;
    const u16* Ag = A + (size_t)(bm + arow) * 128 + acol;
    const u16* Bg = Bt + (size_t)arow * 128 + acol;
    f32x4 zero = {0.f, 0.f, 0.f, 0.f};
    f32x4 acc[4][4];
    #pragma unroll
    for (int i = 0; i < 4; ++i)
        #pragma unroll
        for (int j = 0; j < 4; ++j) acc[i][j] = zero;

    for (int kc = 0; kc < 4; ++kc) {
        __syncthreads();
        GLL(Ag + kc * 32,            As + t * 8);
        GLL(Ag + 64 * 128 + kc * 32, As + 2048 + t * 8);
        GLL(Bg + kc * 32,            Bs + t * 8);
        GLL(Bg + 64 * 128 + kc * 32, Bs + 2048 + t * 8);
        __syncthreads();
        bf16x8 af[4], bfr[4];
        #pragma unroll
        for (int i = 0; i < 4; ++i)
            af[i] = *(const bf16x8*)&As[(wm * 64 + i * 16 + r) * 32 + q * 8];
        #pragma unroll
        for (int j = 0; j < 4; ++j)
            bfr[j] = *(const bf16x8*)&Bs[(wn * 64 + j * 16 + r) * 32 + q * 8];
        #pragma unroll
        for (int i = 0; i < 4; ++i)
            #pragma unroll
            for (int j = 0; j < 4; ++j)
                acc[i][j] = __builtin_amdgcn_mfma_f32_16x16x32_bf16(af[i], bfr[j], acc[i][j], 0, 0, 0);
    }
    #pragma unroll
    for (int i = 0; i < 4; ++i) {
        int rowb = bm + wm * 64 + i * 16 + q * 4;
        #pragma unroll
        for (int j = 0; j < 4; ++j) {
            int colg = wn * 64 + j * 16 + r;
            if (colg >= N) continue;
            float bv = bias[colg];
            #pragma unroll
            for (int rr = 0; rr < 4; ++rr) {
                int rowg = rowb + rr;
                if (rowg < M) {
                    float val = acc[i][j][rr] + bv;
                    if (flags & 1) val = fmaxf(val, 0.f);
                    if (flags & 2) ((u16*)Dv)[(size_t)rowg * ldc + colg] = f2bf(val);
                    else           ((float*)Dv)[(size_t)rowg * ldc + colg] = val;
                }
            }
        }
    }
}

// ============ bond t1 (bf16): T1[e,128] = relu(u[row]+v[col]+pvr*w512+pvc*w513) ============
__global__ void k_bond_t1(const int* __restrict__ ei, const int* __restrict__ pvarr,
                          const u16* __restrict__ uv,
                          const float* __restrict__ bc_w1, u16* __restrict__ T1)
{
    int idx = blockIdx.x * blockDim.x + threadIdx.x;
    if (idx >= N_EDGES * 32) return;
    int el = idx >> 5, q = idx & 31;
    int row = ei[el], col = ei[N_EDGES + el];
    float pvr = (float)pvarr[row], pvc = (float)pvarr[col];
    ushort4 uu = *(const ushort4*)&uv[(size_t)row * 256 + q * 4];
    ushort4 vv = *(const ushort4*)&uv[(size_t)col * 256 + 128 + q * 4];
    float4 w5 = *(const float4*)&bc_w1[512 * 128 + q * 4];
    float4 w6 = *(const float4*)&bc_w1[513 * 128 + q * 4];
    ushort4 o;
    o.x = f2bf(fmaxf(bf2f(uu.x) + bf2f(vv.x) + pvr * w5.x + pvc * w6.x, 0.f));
    o.y = f2bf(fmaxf(bf2f(uu.y) + bf2f(vv.y) + pvr * w5.y + pvc * w6.y, 0.f));
    o.z = f2bf(fmaxf(bf2f(uu.z) + bf2f(vv.z) + pvr * w5.z + pvc * w6.z, 0.f));
    o.w = f2bf(fmaxf(bf2f(uu.w) + bf2f(vv.w) + pvr * w5.w + pvc * w6.w, 0.f));
    *(ushort4*)&T1[(size_t)el * 128 + q * 4] = o;
}

// ============ bond out (T2 bf16) ============
__global__ __launch_bounds__(256) void k_bond_out(const u16* __restrict__ T2, const int* __restrict__ ei,
                           const int* __restrict__ types, const int* __restrict__ pvarr,
                           const float* __restrict__ bc_w3, const float* __restrict__ bc_b3,
                           float* __restrict__ bl_out)
{
    __shared__ float W3s[256];
    __shared__ float b3s[4];
    int tid = threadIdx.x;
    W3s[tid] = bc_w3[tid];
    if (tid < 4) b3s[tid] = bc_b3[tid];
    __syncthreads();
    int el = blockIdx.x * blockDim.x + tid;
    if (el >= N_EDGES) return;
    const u16* t2 = T2 + (size_t)el * 64;
    float a0 = b3s[0], a1 = b3s[1], a2 = b3s[2], a3 = b3s[3];
    for (int k = 0; k < 64; k += 4) {
        ushort4 t4 = *(const ushort4*)&t2[k];
        float tx = bf2f(t4.x), ty = bf2f(t4.y), tz = bf2f(t4.z), tw = bf2f(t4.w);
        a0 += tx * W3s[(k + 0) * 4 + 0]; a1 += tx * W3s[(k + 0) * 4 + 1];
        a2 += tx * W3s[(k + 0) * 4 + 2]; a3 += tx * W3s[(k + 0) * 4 + 3];
        a0 += ty * W3s[(k + 1) * 4 + 0]; a1 += ty * W3s[(k + 1) * 4 + 1];
        a2 += ty * W3s[(k + 1) * 4 + 2]; a3 += ty * W3s[(k + 1) * 4 + 3];
        a0 += tz * W3s[(k + 2) * 4 + 0]; a1 += tz * W3s[(k + 2) * 4 + 1];
        a2 += tz * W3s[(k + 2) * 4 + 2]; a3 += tz * W3s[(k + 2) * 4 + 3];
        a0 += tw * W3s[(k + 3) * 4 + 0]; a1 += tw * W3s[(k + 3) * 4 + 1];
        a2 += tw * W3s[(k + 3) * 4 + 2]; a3 += tw * W3s[(k + 3) * 4 + 3];
    }
    int row = ei[el], col = ei[N_EDGES + el];
    int tr = types[row], tc = types[col];
    int pr = pvarr[row], pc = pvarr[col];
    float halogen = (tr == 4 || tr == 5 || tc == 4 || tc == 5) ? 1.f : 0.f;
    float l1 = (pr <= 1 || pc <= 1) ? 1.f : 0.f;
    float l2 = (pr <= 2 || pc <= 2) ? 1.f : 0.f;
    float pen13 = -100.f * halogen - 50.f * l1;
    a1 += pen13;
    a3 += pen13;
    a2 += pen13 - 50.f * l2;
    float4 o = make_float4(a0, a1, a2, a3);
    *(float4*)&bl_out[(size_t)el * 4] = o;
}

// ================================================================
extern "C" void kernel_launch(void* const* d_in, const int* in_sizes, int n_in,
                              void* d_out, int out_size, void* d_ws, size_t ws_size,
                              hipStream_t stream)
{
    const float* x          = (const float*)d_in[0];
    const float* edge_attr  = (const float*)d_in[1];
    const float* atom_emb   = (const float*)d_in[2];
    const float* bond_emb   = (const float*)d_in[3];
    const float* vp_w1      = (const float*)d_in[4];
    const float* vp_b1      = (const float*)d_in[5];
    const float* vp_w2      = (const float*)d_in[6];
    const float* vp_b2      = (const float*)d_in[7];
    const float* gnn_wself  = (const float*)d_in[8];
    const float* gnn_bself  = (const float*)d_in[9];
    const float* gnn_wmsg   = (const float*)d_in[10];
    const float* gnn_bmsg   = (const float*)d_in[11];
    const float* bc_w1      = (const float*)d_in[12];
    const float* bc_b1      = (const float*)d_in[13];
    const float* bc_w2      = (const float*)d_in[14];
    const float* bc_b2      = (const float*)d_in[15];
    const float* bc_w3      = (const float*)d_in[16];
    const float* bc_b3      = (const float*)d_in[17];
    const float* cp_w1      = (const float*)d_in[18];
    const float* cp_b1      = (const float*)d_in[19];
    const float* cp_w2      = (const float*)d_in[20];
    const float* cp_b2      = (const float*)d_in[21];
    const int*   ei         = (const int*)d_in[22];

    float* out    = (float*)d_out;
    float* h_out  = out + H_OFF;
    float* cp_out = out + CP_OFF;
    float* vl_out = out + VL_OFF;
    float* bl_out = out + BL_OFF;
    float* vi_out = out + VI_OFF;

    // ---- workspace layout ----
    char* base = (char*)d_ws;
    const size_t S = (size_t)M_PAD * 256 * 2;   // 51,249,152 B
    u16* h_bf  = (u16*)(base + 0 * S);           // R0: h ; later uv
    u16* uv_bf = (u16*)(base + 0 * S);
    u16* hm_bf = (u16*)(base + 1 * S);           // R1: hm ; later T1 (spans R1+R2)
    u16* hs_bf = (u16*)(base + 2 * S);           // R2: hs
    u16* T1    = (u16*)(base + 1 * S);           // E_PAD*128*2 = 76.8 MB <= 2S
    u16* hd_bf = (u16*)(base + 3 * S);           // R3: hd ; later T2
    u16* T2    = (u16*)(base + 3 * S);           // E_PAD*64*2 = 38.4 MB <= S
    u16* cp1_bf= (u16*)(base + 4 * S);           // R4: [M_PAD][128] bf16 = 25.6 MB
    char* w    = base + 4 * S + (size_t)M_PAD * 128 * 2;
    int* degree  = (int*)w; w += (size_t)N_NODES * 4;
    int* offsets = (int*)w; w += (size_t)N_NODES * 4;
    int* cursor  = (int*)w; w += (size_t)N_NODES * 4;
    int* types   = (int*)w; w += (size_t)N_NODES * 4;
    int* pvarr   = (int*)w; w += (size_t)N_NODES * 4;
    int* csr     = (int*)w; w += (size_t)N_EDGES * 4;
    int* bsum    = (int*)w; w += 4096;
    int* bbase   = (int*)w; w += 4096;
    int* pv_tab  = (int*)w; w += 1024;
    float* vl_tab    = (float*)w; w += 2048;
    float* h0_tab    = (float*)w; w += 11 * 256 * 4;
    float* self0_tab = (float*)w; w += 11 * 256 * 4;
    float* msg0_tab  = (float*)w; w += 55 * 256 * 4;
    float* bondtab   = (float*)w; w += 2 * 5 * 256 * 4;
    u16* BtL1  = (u16*)w; w += 512 * 256 * 2;
    u16* BtL2  = (u16*)w; w += 512 * 256 * 2;
    u16* Bt3   = (u16*)w; w += 384 * 256 * 2;
    u16* BtW2  = (u16*)w; w += 128 * 128 * 2;
    u16* BtCP2 = (u16*)w; w += 128 * 128 * 2;
    float* bias512  = (float*)w; w += 2 * 512 * 4;
    float* biasPost = (float*)w; w += 384 * 4;

    // ---- setup ----
    k_type_mlp<<<1, 256, 0, stream>>>(atom_emb, vp_w1, vp_b1, vp_w2, vp_b2, pv_tab, vl_tab, h0_tab);
    k_tables<<<76, 256, 0, stream>>>(bond_emb, gnn_wself, gnn_bself, gnn_wmsg, gnn_bmsg,
                                     h0_tab, self0_tab, msg0_tab, bondtab);
    k_wtrans<<<1664, 256, 0, stream>>>(gnn_wmsg, gnn_wself, bc_w1, cp_w1, bc_w2, cp_w2,
                                       BtL1, BtL2, Bt3, BtW2, BtCP2);
    k_setup_bias<<<6, 256, 0, stream>>>(gnn_bself, bc_b1, cp_b1, bias512, biasPost);
    k_node_init<<<(N_NODES + 255) / 256, 256, 0, stream>>>(x, pv_tab, vl_tab, types, pvarr, degree, vl_out);
    k_edge_deg<<<(N_EDGES + 255) / 256, 256, 0, stream>>>(ei, degree);
    int nb = (N_NODES + SCAN_B - 1) / SCAN_B;
    k_scan1<<<nb, SCAN_B, 0, stream>>>(degree, offsets, bsum);
    k_scan2<<<1, 128, 0, stream>>>(bsum, bbase, nb);
    k_scan3<<<nb, SCAN_B, 0, stream>>>(offsets, bbase, cursor);
    k_csr_fill<<<(N_EDGES + 255) / 256, 256, 0, stream>>>(ei, edge_attr, types, cursor, csr);
    k_agg0<<<N_NODES / 4, 256, 0, stream>>>(offsets, degree, types, self0_tab, msg0_tab, csr, h_bf);

    // ---- GNN layers 1,2 ----
    const int MT = M_PAD / 128;  // 782
    for (int l = 1; l <= 2; ++l) {
        const u16* BtL = (l == 1) ? BtL1 : BtL2;
        k_gemm_layer<<<MT, 256, 0, stream>>>(h_bf, BtL, bias512 + (size_t)(l - 1) * 512,
                                             hm_bf, hs_bf, N_NODES);
        k_agg12<<<N_NODES / 4, 256, 0, stream>>>(offsets, degree, hs_bf, hm_bf,
                                                 bondtab + (size_t)(l - 1) * 5 * 256, csr, h_bf);
    }

    // ---- damp ----
    k_damp<<<(N_NODES * 64 + 255) / 256, 256, 0, stream>>>(h_bf, degree, pvarr, h_out, hd_bf, vi_out);

    // ---- uv + cp1 fused; then cp2 ----
    k_gemm_post3<<<MT, 256, 0, stream>>>(hd_bf, Bt3, biasPost, uv_bf, cp1_bf, N_NODES);
    k_gemm_k128<<<MT, 256, 0, stream>>>(cp1_bf, BtCP2, cp_b2, cp_out, 32, N_NODES, 32, 0);

    // ---- bond chain (single pass) ----
    k_bond_t1<<<(N_EDGES * 32 + 255) / 256, 256, 0, stream>>>(ei, pvarr, uv_bf, bc_w1, T1);
    k_gemm_k128<<<E_PAD / 128, 256, 0, stream>>>(T1, BtW2, bc_b2, T2, 64, N_EDGES, 64, 3);
    k_bond_out<<<(N_EDGES + 255) / 256, 256, 0, stream>>>(T2, ei, types, pvarr, bc_w3, bc_b3, bl_out);
}

// Round 4
// 739.820 us; speedup vs baseline: 2.3827x; 1.1276x over previous
//
#include <hip/hip_runtime.h>

#define N_NODES 100000
#define N_EDGES 300000
#define M_PAD   100096   // 782*128
#define E_PAD   300032   // 2344*128

typedef unsigned short u16;
typedef short bf16x8 __attribute__((ext_vector_type(8)));
typedef float f32x4  __attribute__((ext_vector_type(4)));

__device__ __forceinline__ float bf2f(u16 u) {
    unsigned x = ((unsigned)u) << 16;
    return __builtin_bit_cast(float, x);
}
__device__ __forceinline__ u16 f2bf(float f) {
    unsigned u = __builtin_bit_cast(unsigned, f);
    unsigned r = (u + 0x7FFF + ((u >> 16) & 1)) >> 16;
    return (u16)r;
}

// ---------------- output layout (floats) ----------------
#define H_OFF   0
#define CP_OFF  25600000
#define VL_OFF  28800000
#define BL_OFF  29600000
#define VI_OFF  30800000

#define GLL(gp, lp) __builtin_amdgcn_global_load_lds( \
    (const __attribute__((address_space(1))) unsigned int*)(gp), \
    (__attribute__((address_space(3))) unsigned int*)(lp), 16, 0, 0)

// ============ per-atom-type valence MLP + h0 rows ============
__global__ void k_type_mlp(const float* __restrict__ atom_emb,
                           const float* __restrict__ vp_w1, const float* __restrict__ vp_b1,
                           const float* __restrict__ vp_w2, const float* __restrict__ vp_b2,
                           int* __restrict__ pv_tab, float* __restrict__ vl_tab,
                           float* __restrict__ h0_tab)
{
    int tid = threadIdx.x;
    for (int i = tid; i < 11 * 256; i += 256) h0_tab[i] = 0.f;
    __syncthreads();
    if (tid < 11) {
        int t = tid;
        const float* ae = atom_emb + t * 64;
        float lg[8];
        #pragma unroll
        for (int c = 0; c < 8; ++c) lg[c] = vp_b2[c];
        for (int j = 0; j < 32; ++j) {
            float z = vp_b1[j];
            for (int d = 0; d < 64; ++d) z += ae[d] * vp_w1[d * 32 + j];
            z = fmaxf(z, 0.f);
            #pragma unroll
            for (int c = 0; c < 8; ++c) lg[c] += z * vp_w2[j * 8 + c];
        }
        int best = 0;
        #pragma unroll
        for (int c = 1; c < 8; ++c) if (lg[c] > lg[best]) best = c;
        pv_tab[t] = best + 1;
        for (int c = 0; c < 8; ++c) vl_tab[t * 8 + c] = lg[c];
        float* h0 = h0_tab + t * 256;
        for (int d = 0; d < 64; ++d) h0[d] = ae[d];
        h0[64 + best] = 1.f;
    }
}

// ============ layer-0 tables + bond tables for layers 1,2 ============
__global__ void k_tables(const float* __restrict__ bond_emb,
                         const float* __restrict__ gnn_wself, const float* __restrict__ gnn_bself,
                         const float* __restrict__ gnn_wmsg, const float* __restrict__ gnn_bmsg,
                         const float* __restrict__ h0_tab,
                         float* __restrict__ self0_tab, float* __restrict__ msg0_tab,
                         float* __restrict__ bondtab)
{
    int b = blockIdx.x, c = threadIdx.x;
    if (b < 11) {
        int t = b;
        const float* h0 = h0_tab + t * 256;
        float acc = gnn_bself[c];
        for (int k = 0; k < 256; ++k) acc += h0[k] * gnn_wself[k * 256 + c];
        self0_tab[t * 256 + c] = acc;
    } else if (b < 66) {
        int idx = b - 11; int t = idx / 5, bb = idx % 5;
        const float* h0 = h0_tab + t * 256;
        float acc = gnn_bmsg[c];
        for (int k = 0; k < 256; ++k) acc += h0[k] * gnn_wmsg[k * 256 + c];
        const float* be = bond_emb + bb * 64;
        for (int k = 0; k < 64; ++k) acc += be[k] * gnn_wmsg[(256 + k) * 256 + c];
        msg0_tab[idx * 256 + c] = fmaxf(acc, 0.f);
    } else {
        int idx = b - 66; int l = idx / 5 + 1, bb = idx % 5;
        const float* w = gnn_wmsg + (size_t)l * 320 * 256;
        const float* be = bond_emb + bb * 64;
        float acc = gnn_bmsg[l * 256 + c];
        for (int k = 0; k < 64; ++k) acc += be[k] * w[(256 + k) * 256 + c];
        bondtab[(l - 1) * 5 * 256 + bb * 256 + c] = acc;
    }
}

// ============ bf16-transposed weight tables ============
__global__ void k_wtrans(const float* __restrict__ wmsg, const float* __restrict__ wself,
                         const float* __restrict__ bcw1, const float* __restrict__ cpw1,
                         const float* __restrict__ bcw2, const float* __restrict__ cpw2,
                         u16* __restrict__ BtL1, u16* __restrict__ BtL2, u16* __restrict__ Bt3,
                         u16* __restrict__ BtW2, u16* __restrict__ BtCP2)
{
    int b = blockIdx.x, k = threadIdx.x;
    if (b < 512) {
        int n = b;
        float v = (n < 256) ? wmsg[(size_t)1 * 320 * 256 + (size_t)k * 256 + n]
                            : wself[(size_t)1 * 256 * 256 + (size_t)k * 256 + (n - 256)];
        BtL1[n * 256 + k] = f2bf(v);
    } else if (b < 1024) {
        int n = b - 512;
        float v = (n < 256) ? wmsg[(size_t)2 * 320 * 256 + (size_t)k * 256 + n]
                            : wself[(size_t)2 * 256 * 256 + (size_t)k * 256 + (n - 256)];
        BtL2[n * 256 + k] = f2bf(v);
    } else if (b < 1408) {
        int n = b - 1024;
        float v;
        if (n < 128)      v = bcw1[k * 128 + n];
        else if (n < 256) v = bcw1[(256 + k) * 128 + (n - 128)];
        else              v = cpw1[k * 128 + (n - 256)];
        Bt3[n * 256 + k] = f2bf(v);
    } else if (b < 1536) {
        int n = b - 1408;
        if (k < 128) BtW2[n * 128 + k] = f2bf(n < 64 ? bcw2[k * 64 + n] : 0.f);
    } else {
        int n = b - 1536;
        if (k < 128) BtCP2[n * 128 + k] = f2bf(n < 32 ? cpw2[k * 32 + n] : 0.f);
    }
}

__global__ void k_setup_bias(const float* __restrict__ bself, const float* __restrict__ bcb1,
                             const float* __restrict__ cpb1,
                             float* __restrict__ bias512, float* __restrict__ biasPost)
{
    int i = blockIdx.x * 256 + threadIdx.x;
    if (i < 1024) {
        int l = i >> 9, c = i & 511;
        bias512[l * 512 + c] = (c < 256) ? 0.f : bself[(l + 1) * 256 + (c - 256)];
    } else if (i < 1408) {
        int c = i - 1024;
        biasPost[c] = (c < 128) ? bcb1[c] : ((c < 256) ? 0.f : cpb1[c - 256]);
    }
}

// ============ node init ============
__global__ void k_node_init(const float* __restrict__ x, const int* __restrict__ pv_tab,
                            const float* __restrict__ vl_tab,
                            int* __restrict__ types, int* __restrict__ pvarr,
                            int* __restrict__ degree, float* __restrict__ vl_out)
{
    int i = blockIdx.x * blockDim.x + threadIdx.x;
    if (i >= N_NODES) return;
    int t = (int)x[i * 16];
    t = min(max(t, 0), 10);
    types[i] = t;
    pvarr[i] = pv_tab[t];
    degree[i] = 0;
    float4 v0 = *(const float4*)&vl_tab[t * 8];
    float4 v1 = *(const float4*)&vl_tab[t * 8 + 4];
    *(float4*)&vl_out[i * 8]     = v0;
    *(float4*)&vl_out[i * 8 + 4] = v1;
}

__global__ void k_edge_deg(const int* __restrict__ ei, int* __restrict__ degree)
{
    int e = blockIdx.x * blockDim.x + threadIdx.x;
    if (e >= N_EDGES) return;
    atomicAdd(&degree[ei[e]], 1);
}

// ============ scan ============
#define SCAN_B 1024
__global__ void k_scan1(const int* __restrict__ degree, int* __restrict__ part, int* __restrict__ bsum)
{
    __shared__ int s[SCAN_B];
    int tid = threadIdx.x;
    int i = blockIdx.x * SCAN_B + tid;
    int v = (i < N_NODES) ? degree[i] : 0;
    s[tid] = v; __syncthreads();
    for (int off = 1; off < SCAN_B; off <<= 1) {
        int t = (tid >= off) ? s[tid - off] : 0;
        __syncthreads();
        s[tid] += t;
        __syncthreads();
    }
    if (i < N_NODES) part[i] = s[tid] - v;
    if (tid == SCAN_B - 1) bsum[blockIdx.x] = s[tid];
}

__global__ void k_scan2(const int* __restrict__ bsum, int* __restrict__ bbase, int nb)
{
    __shared__ int s[128];
    int tid = threadIdx.x;
    int v = (tid < nb) ? bsum[tid] : 0;
    s[tid] = v; __syncthreads();
    for (int off = 1; off < 128; off <<= 1) {
        int t = (tid >= off) ? s[tid - off] : 0;
        __syncthreads();
        s[tid] += t;
        __syncthreads();
    }
    bbase[tid] = s[tid] - v;
}

__global__ void k_scan3(int* __restrict__ part, const int* __restrict__ bbase, int* __restrict__ cursor)
{
    int i = blockIdx.x * SCAN_B + threadIdx.x;
    if (i >= N_NODES) return;
    int o = part[i] + bbase[blockIdx.x];
    part[i] = o;
    cursor[i] = o;
}

// ============ CSR fill ============
__global__ void k_csr_fill(const int* __restrict__ ei, const float* __restrict__ edge_attr,
                           const int* __restrict__ types, int* __restrict__ cursor,
                           int* __restrict__ csr)
{
    int e = blockIdx.x * blockDim.x + threadIdx.x;
    if (e >= N_EDGES) return;
    int row = ei[e], col = ei[N_EDGES + e];
    int bt = (int)edge_attr[e * 4];
    bt = min(max(bt, 0), 4);
    int pos = atomicAdd(&cursor[row], 1);
    csr[pos] = col | (bt << 20) | (types[col] << 24);
}

// ============ layer-0 aggregation (tables) -> h bf16 ============
__global__ __launch_bounds__(256) void k_agg0(const int* __restrict__ offsets, const int* __restrict__ degree,
                       const int* __restrict__ types,
                       const float* __restrict__ self0_tab, const float* __restrict__ msg0_tab,
                       const int* __restrict__ csr, u16* __restrict__ h)
{
    int wid = threadIdx.x >> 6, lane = threadIdx.x & 63;
    int node = blockIdx.x * 4 + wid;
    if (node >= N_NODES) return;
    int t = types[node];
    float4 acc = *(const float4*)&self0_tab[t * 256 + lane * 4];
    int start = offsets[node], deg = degree[node];
    for (int j = 0; j < deg; ++j) {
        int p = csr[start + j];
        int combo = ((p >> 24) & 0xF) * 5 + ((p >> 20) & 7);
        float4 m = *(const float4*)&msg0_tab[combo * 256 + lane * 4];
        acc.x += m.x; acc.y += m.y; acc.z += m.z; acc.w += m.w;
    }
    ushort4 r;
    r.x = f2bf(fmaxf(acc.x, 0.f)); r.y = f2bf(fmaxf(acc.y, 0.f));
    r.z = f2bf(fmaxf(acc.z, 0.f)); r.w = f2bf(fmaxf(acc.w, 0.f));
    *(ushort4*)&h[(size_t)node * 256 + lane * 4] = r;
}

// ============ layers 1,2 aggregation ============
__global__ __launch_bounds__(256) void k_agg12(const int* __restrict__ offsets, const int* __restrict__ degree,
                        const u16* __restrict__ hs, const u16* __restrict__ hm,
                        const float* __restrict__ bondtab, const int* __restrict__ csr,
                        u16* __restrict__ h)
{
    int wid = threadIdx.x >> 6, lane = threadIdx.x & 63;
    int node = blockIdx.x * 4 + wid;
    if (node >= N_NODES) return;
    ushort4 s4 = *(const ushort4*)&hs[(size_t)node * 256 + lane * 4];
    float ax = bf2f(s4.x), ay = bf2f(s4.y), az = bf2f(s4.z), aw = bf2f(s4.w);
    int start = offsets[node], deg = degree[node];
    for (int j = 0; j < deg; ++j) {
        int p = csr[start + j];
        int c = p & 0xFFFFF;
        int bt = (p >> 20) & 7;
        ushort4 m4 = *(const ushort4*)&hm[(size_t)c * 256 + lane * 4];
        float4 bb = *(const float4*)&bondtab[bt * 256 + lane * 4];
        ax += fmaxf(bf2f(m4.x) + bb.x, 0.f);
        ay += fmaxf(bf2f(m4.y) + bb.y, 0.f);
        az += fmaxf(bf2f(m4.z) + bb.z, 0.f);
        aw += fmaxf(bf2f(m4.w) + bb.w, 0.f);
    }
    ushort4 r;
    r.x = f2bf(fmaxf(ax, 0.f)); r.y = f2bf(fmaxf(ay, 0.f));
    r.z = f2bf(fmaxf(az, 0.f)); r.w = f2bf(fmaxf(aw, 0.f));
    *(ushort4*)&h[(size_t)node * 256 + lane * 4] = r;
}

// ============ violations + damping ============
__global__ void k_damp(const u16* __restrict__ h, const int* __restrict__ degree,
                       const int* __restrict__ pvarr,
                       float* __restrict__ h_out, u16* __restrict__ hd_bf,
                       float* __restrict__ viol_out)
{
    int idx = blockIdx.x * blockDim.x + threadIdx.x;
    if (idx >= N_NODES * 64) return;
    int i = idx >> 6, q = idx & 63;
    float viol = fmaxf((float)degree[i] - (float)pvarr[i], 0.f);
    float s = 1.f / (1.f + viol);
    ushort4 v4 = *(const ushort4*)&h[(size_t)i * 256 + q * 4];
    float4 v;
    v.x = bf2f(v4.x) * s; v.y = bf2f(v4.y) * s; v.z = bf2f(v4.z) * s; v.w = bf2f(v4.w) * s;
    *(float4*)&h_out[(size_t)i * 256 + q * 4] = v;
    ushort4 r;
    r.x = f2bf(v.x); r.y = f2bf(v.y); r.z = f2bf(v.z); r.w = f2bf(v.w);
    *(ushort4*)&hd_bf[(size_t)i * 256 + q * 4] = r;
    if (q == 0) viol_out[i] = viol;
}

// ================== layer GEMM, 2-barrier 16KB-LDS structure + XCD swizzle ==================
// grid: 98*32 blocks. Decode: nt = (b&31)>>3, m = (b>>5)*8 + (b&7).
// Same-m blocks have equal b%8 (same XCD) and are temporally adjacent -> A-tile L2 reuse.
__global__ __launch_bounds__(256) void k_gemm_dual(
    const u16* __restrict__ A, const u16* __restrict__ Bt,
    const float* __restrict__ bias512,
    u16* __restrict__ Dm, u16* __restrict__ Ds, int M, int MT)
{
    __shared__ u16 As[128 * 32];
    __shared__ u16 Bs[128 * 32];
    int b = blockIdx.x;
    int rsub = b & 31;
    int nt = rsub >> 3, m8 = rsub & 7;
    int mt = (b >> 5) * 8 + m8;
    if (mt >= MT) return;
    int bm = mt * 128, bn = nt * 128;

    int t = threadIdx.x;
    int lane = t & 63, w = t >> 6;
    int wm = w & 1, wn = w >> 1;
    f32x4 zero = {0.f, 0.f, 0.f, 0.f};
    f32x4 acc[4][4];
    #pragma unroll
    for (int i = 0; i < 4; ++i)
        #pragma unroll
        for (int j = 0; j < 4; ++j) acc[i][j] = zero;

    int arow = t >> 2, acol = (t & 3) * 8;
    const u16* Ag = A + (size_t)(bm + arow) * 256 + acol;
    const u16* Bg = Bt + (size_t)(bn + arow) * 256 + acol;
    u16* Asp = As + t * 8;
    u16* Bsp = Bs + t * 8;
    int q = lane >> 4, r = lane & 15;

    for (int k0 = 0; k0 < 256; k0 += 32) {
        __syncthreads();
        GLL(Ag + k0,            Asp);
        GLL(Ag + 64 * 256 + k0, Asp + 2048);
        GLL(Bg + k0,            Bsp);
        GLL(Bg + 64 * 256 + k0, Bsp + 2048);
        __syncthreads();
        bf16x8 af[4], bfr[4];
        #pragma unroll
        for (int i = 0; i < 4; ++i)
            af[i] = *(const bf16x8*)&As[(wm * 64 + i * 16 + r) * 32 + q * 8];
        #pragma unroll
        for (int j = 0; j < 4; ++j)
            bfr[j] = *(const bf16x8*)&Bs[(wn * 64 + j * 16 + r) * 32 + q * 8];
        #pragma unroll
        for (int i = 0; i < 4; ++i)
            #pragma unroll
            for (int j = 0; j < 4; ++j)
                acc[i][j] = __builtin_amdgcn_mfma_f32_16x16x32_bf16(af[i], bfr[j], acc[i][j], 0, 0, 0);
    }
    #pragma unroll
    for (int i = 0; i < 4; ++i) {
        int rowb = bm + wm * 64 + i * 16 + q * 4;
        #pragma unroll
        for (int j = 0; j < 4; ++j) {
            int colg = bn + wn * 64 + j * 16 + r;
            float bv = bias512[colg];
            u16* D = (colg < 256) ? Dm : Ds;
            int col = colg & 255;
            #pragma unroll
            for (int rr = 0; rr < 4; ++rr) {
                int rowg = rowb + rr;
                if (rowg < M) D[(size_t)rowg * 256 + col] = f2bf(acc[i][j][rr] + bv);
            }
        }
    }
}

// ================== post GEMM (N=384: uv 256 bf16 + cp1 128 bf16-relu), swizzled ==================
// grid: 98*24. Decode: rsub = b%24; nt = rsub/8; m = (b/24)*8 + rsub%8.
__global__ __launch_bounds__(256) void k_gemm_post(
    const u16* __restrict__ A, const u16* __restrict__ Bt3,
    const float* __restrict__ biasPost,
    u16* __restrict__ UV, u16* __restrict__ CP1, int M, int MT)
{
    __shared__ u16 As[128 * 32];
    __shared__ u16 Bs[128 * 32];
    int b = blockIdx.x;
    int rsub = b % 24;
    int nt = rsub >> 3, m8 = rsub & 7;
    int mt = (b / 24) * 8 + m8;
    if (mt >= MT) return;
    int bm = mt * 128, bn = nt * 128;

    int t = threadIdx.x;
    int lane = t & 63, w = t >> 6;
    int wm = w & 1, wn = w >> 1;
    f32x4 zero = {0.f, 0.f, 0.f, 0.f};
    f32x4 acc[4][4];
    #pragma unroll
    for (int i = 0; i < 4; ++i)
        #pragma unroll
        for (int j = 0; j < 4; ++j) acc[i][j] = zero;

    int arow = t >> 2, acol = (t & 3) * 8;
    const u16* Ag = A + (size_t)(bm + arow) * 256 + acol;
    const u16* Bg = Bt3 + (size_t)(bn + arow) * 256 + acol;
    u16* Asp = As + t * 8;
    u16* Bsp = Bs + t * 8;
    int q = lane >> 4, r = lane & 15;

    for (int k0 = 0; k0 < 256; k0 += 32) {
        __syncthreads();
        GLL(Ag + k0,            Asp);
        GLL(Ag + 64 * 256 + k0, Asp + 2048);
        GLL(Bg + k0,            Bsp);
        GLL(Bg + 64 * 256 + k0, Bsp + 2048);
        __syncthreads();
        bf16x8 af[4], bfr[4];
        #pragma unroll
        for (int i = 0; i < 4; ++i)
            af[i] = *(const bf16x8*)&As[(wm * 64 + i * 16 + r) * 32 + q * 8];
        #pragma unroll
        for (int j = 0; j < 4; ++j)
            bfr[j] = *(const bf16x8*)&Bs[(wn * 64 + j * 16 + r) * 32 + q * 8];
        #pragma unroll
        for (int i = 0; i < 4; ++i)
            #pragma unroll
            for (int j = 0; j < 4; ++j)
                acc[i][j] = __builtin_amdgcn_mfma_f32_16x16x32_bf16(af[i], bfr[j], acc[i][j], 0, 0, 0);
    }
    #pragma unroll
    for (int i = 0; i < 4; ++i) {
        int rowb = bm + wm * 64 + i * 16 + q * 4;
        #pragma unroll
        for (int j = 0; j < 4; ++j) {
            int coll = wn * 64 + j * 16 + r;
            float bv = biasPost[bn + coll];
            #pragma unroll
            for (int rr = 0; rr < 4; ++rr) {
                int rowg = rowb + rr;
                if (rowg < M) {
                    float val = acc[i][j][rr] + bv;
                    if (nt < 2) UV[(size_t)rowg * 256 + bn + coll] = f2bf(val);
                    else        CP1[(size_t)rowg * 128 + coll] = f2bf(fmaxf(val, 0.f));
                }
            }
        }
    }
}

// ================== small K=128 MFMA GEMM (tile 128x128, N<=128) ==================
// flags: bit0 = relu, bit1 = bf16 out
__global__ __launch_bounds__(256) void k_gemm_k128(
    const u16* __restrict__ A, const u16* __restrict__ Bt,
    const float* __restrict__ bias, void* __restrict__ Dv,
    int ldc, int M, int N, int flags)
{
    __shared__ u16 As[4096];
    __shared__ u16 Bs[4096];
    int t = threadIdx.x;
    int lane = t & 63, w = t >> 6;
    int wm = w & 1, wn = w >> 1;
    int bm = blockIdx.x * 128;
    int arow = t >> 2, acol = (t & 3) * 8;
    int q = lane >> 4, r = lane & 15;
    const u16* Ag = A + (size_t)(bm + arow) * 128 + acol;
    const u16* Bg = Bt + (size_t)arow * 128 + acol;
    f32x4 zero = {0.f, 0.f, 0.f, 0.f};
    f32x4 acc[4][4];
    #pragma unroll
    for (int i = 0; i < 4; ++i)
        #pragma unroll
        for (int j = 0; j < 4; ++j) acc[i][j] = zero;

    for (int kc = 0; kc < 4; ++kc) {
        __syncthreads();
        GLL(Ag + kc * 32,            As + t * 8);
        GLL(Ag + 64 * 128 + kc * 32, As + 2048 + t * 8);
        GLL(Bg + kc * 32,            Bs + t * 8);
        GLL(Bg + 64 * 128 + kc * 32, Bs + 2048 + t * 8);
        __syncthreads();
        bf16x8 af[4], bfr[4];
        #pragma unroll
        for (int i = 0; i < 4; ++i)
            af[i] = *(const bf16x8*)&As[(wm * 64 + i * 16 + r) * 32 + q * 8];
        #pragma unroll
        for (int j = 0; j < 4; ++j)
            bfr[j] = *(const bf16x8*)&Bs[(wn * 64 + j * 16 + r) * 32 + q * 8];
        #pragma unroll
        for (int i = 0; i < 4; ++i)
            #pragma unroll
            for (int j = 0; j < 4; ++j)
                acc[i][j] = __builtin_amdgcn_mfma_f32_16x16x32_bf16(af[i], bfr[j], acc[i][j], 0, 0, 0);
    }
    #pragma unroll
    for (int i = 0; i < 4; ++i) {
        int rowb = bm + wm * 64 + i * 16 + q * 4;
        #pragma unroll
        for (int j = 0; j < 4; ++j) {
            int colg = wn * 64 + j * 16 + r;
            if (colg >= N) continue;
            float bv = bias[colg];
            #pragma unroll
            for (int rr = 0; rr < 4; ++rr) {
                int rowg = rowb + rr;
                if (rowg < M) {
                    float val = acc[i][j][rr] + bv;
                    if (flags & 1) val = fmaxf(val, 0.f);
                    if (flags & 2) ((u16*)Dv)[(size_t)rowg * ldc + colg] = f2bf(val);
                    else           ((float*)Dv)[(size_t)rowg * ldc + colg] = val;
                }
            }
        }
    }
}

// ============ bond t1 (bf16) ============
__global__ void k_bond_t1(const int* __restrict__ ei, const int* __restrict__ pvarr,
                          const u16* __restrict__ uv,
                          const float* __restrict__ bc_w1, u16* __restrict__ T1)
{
    int idx = blockIdx.x * blockDim.x + threadIdx.x;
    if (idx >= N_EDGES * 32) return;
    int el = idx >> 5, q = idx & 31;
    int row = ei[el], col = ei[N_EDGES + el];
    float pvr = (float)pvarr[row], pvc = (float)pvarr[col];
    ushort4 uu = *(const ushort4*)&uv[(size_t)row * 256 + q * 4];
    ushort4 vv = *(const ushort4*)&uv[(size_t)col * 256 + 128 + q * 4];
    float4 w5 = *(const float4*)&bc_w1[512 * 128 + q * 4];
    float4 w6 = *(const float4*)&bc_w1[513 * 128 + q * 4];
    ushort4 o;
    o.x = f2bf(fmaxf(bf2f(uu.x) + bf2f(vv.x) + pvr * w5.x + pvc * w6.x, 0.f));
    o.y = f2bf(fmaxf(bf2f(uu.y) + bf2f(vv.y) + pvr * w5.y + pvc * w6.y, 0.f));
    o.z = f2bf(fmaxf(bf2f(uu.z) + bf2f(vv.z) + pvr * w5.z + pvc * w6.z, 0.f));
    o.w = f2bf(fmaxf(bf2f(uu.w) + bf2f(vv.w) + pvr * w5.w + pvc * w6.w, 0.f));
    *(ushort4*)&T1[(size_t)el * 128 + q * 4] = o;
}

// ============ bond out (T2 bf16) ============
__global__ __launch_bounds__(256) void k_bond_out(const u16* __restrict__ T2, const int* __restrict__ ei,
                           const int* __restrict__ types, const int* __restrict__ pvarr,
                           const float* __restrict__ bc_w3, const float* __restrict__ bc_b3,
                           float* __restrict__ bl_out)
{
    __shared__ float W3s[256];
    __shared__ float b3s[4];
    int tid = threadIdx.x;
    W3s[tid] = bc_w3[tid];
    if (tid < 4) b3s[tid] = bc_b3[tid];
    __syncthreads();
    int el = blockIdx.x * blockDim.x + tid;
    if (el >= N_EDGES) return;
    const u16* t2 = T2 + (size_t)el * 64;
    float a0 = b3s[0], a1 = b3s[1], a2 = b3s[2], a3 = b3s[3];
    for (int k = 0; k < 64; k += 4) {
        ushort4 t4 = *(const ushort4*)&t2[k];
        float tx = bf2f(t4.x), ty = bf2f(t4.y), tz = bf2f(t4.z), tw = bf2f(t4.w);
        a0 += tx * W3s[(k + 0) * 4 + 0]; a1 += tx * W3s[(k + 0) * 4 + 1];
        a2 += tx * W3s[(k + 0) * 4 + 2]; a3 += tx * W3s[(k + 0) * 4 + 3];
        a0 += ty * W3s[(k + 1) * 4 + 0]; a1 += ty * W3s[(k + 1) * 4 + 1];
        a2 += ty * W3s[(k + 1) * 4 + 2]; a3 += ty * W3s[(k + 1) * 4 + 3];
        a0 += tz * W3s[(k + 2) * 4 + 0]; a1 += tz * W3s[(k + 2) * 4 + 1];
        a2 += tz * W3s[(k + 2) * 4 + 2]; a3 += tz * W3s[(k + 2) * 4 + 3];
        a0 += tw * W3s[(k + 3) * 4 + 0]; a1 += tw * W3s[(k + 3) * 4 + 1];
        a2 += tw * W3s[(k + 3) * 4 + 2]; a3 += tw * W3s[(k + 3) * 4 + 3];
    }
    int row = ei[el], col = ei[N_EDGES + el];
    int tr = types[row], tc = types[col];
    int pr = pvarr[row], pc = pvarr[col];
    float halogen = (tr == 4 || tr == 5 || tc == 4 || tc == 5) ? 1.f : 0.f;
    float l1 = (pr <= 1 || pc <= 1) ? 1.f : 0.f;
    float l2 = (pr <= 2 || pc <= 2) ? 1.f : 0.f;
    float pen13 = -100.f * halogen - 50.f * l1;
    a1 += pen13;
    a3 += pen13;
    a2 += pen13 - 50.f * l2;
    float4 o = make_float4(a0, a1, a2, a3);
    *(float4*)&bl_out[(size_t)el * 4] = o;
}

// ================================================================
extern "C" void kernel_launch(void* const* d_in, const int* in_sizes, int n_in,
                              void* d_out, int out_size, void* d_ws, size_t ws_size,
                              hipStream_t stream)
{
    const float* x          = (const float*)d_in[0];
    const float* edge_attr  = (const float*)d_in[1];
    const float* atom_emb   = (const float*)d_in[2];
    const float* bond_emb   = (const float*)d_in[3];
    const float* vp_w1      = (const float*)d_in[4];
    const float* vp_b1      = (const float*)d_in[5];
    const float* vp_w2      = (const float*)d_in[6];
    const float* vp_b2      = (const float*)d_in[7];
    const float* gnn_wself  = (const float*)d_in[8];
    const float* gnn_bself  = (const float*)d_in[9];
    const float* gnn_wmsg   = (const float*)d_in[10];
    const float* gnn_bmsg   = (const float*)d_in[11];
    const float* bc_w1      = (const float*)d_in[12];
    const float* bc_b1      = (const float*)d_in[13];
    const float* bc_w2      = (const float*)d_in[14];
    const float* bc_b2      = (const float*)d_in[15];
    const float* bc_w3      = (const float*)d_in[16];
    const float* bc_b3      = (const float*)d_in[17];
    const float* cp_w1      = (const float*)d_in[18];
    const float* cp_b1      = (const float*)d_in[19];
    const float* cp_w2      = (const float*)d_in[20];
    const float* cp_b2      = (const float*)d_in[21];
    const int*   ei         = (const int*)d_in[22];

    float* out    = (float*)d_out;
    float* h_out  = out + H_OFF;
    float* cp_out = out + CP_OFF;
    float* vl_out = out + VL_OFF;
    float* bl_out = out + BL_OFF;
    float* vi_out = out + VI_OFF;

    // ---- workspace layout ----
    char* base = (char*)d_ws;
    const size_t S = (size_t)M_PAD * 256 * 2;   // 51,249,152 B
    u16* h_bf  = (u16*)(base + 0 * S);           // R0: h ; later uv
    u16* uv_bf = (u16*)(base + 0 * S);
    u16* hm_bf = (u16*)(base + 1 * S);           // R1: hm ; later T1 (spans R1+R2)
    u16* hs_bf = (u16*)(base + 2 * S);           // R2: hs
    u16* T1    = (u16*)(base + 1 * S);           // E_PAD*128*2 = 76.8 MB <= 2S
    u16* hd_bf = (u16*)(base + 3 * S);           // R3: hd ; later T2
    u16* T2    = (u16*)(base + 3 * S);           // E_PAD*64*2 = 38.4 MB <= S
    u16* cp1_bf= (u16*)(base + 4 * S);           // R4: [M_PAD][128] bf16 = 25.6 MB
    char* w    = base + 4 * S + (size_t)M_PAD * 128 * 2;
    int* degree  = (int*)w; w += (size_t)N_NODES * 4;
    int* offsets = (int*)w; w += (size_t)N_NODES * 4;
    int* cursor  = (int*)w; w += (size_t)N_NODES * 4;
    int* types   = (int*)w; w += (size_t)N_NODES * 4;
    int* pvarr   = (int*)w; w += (size_t)N_NODES * 4;
    int* csr     = (int*)w; w += (size_t)N_EDGES * 4;
    int* bsum    = (int*)w; w += 4096;
    int* bbase   = (int*)w; w += 4096;
    int* pv_tab  = (int*)w; w += 1024;
    float* vl_tab    = (float*)w; w += 2048;
    float* h0_tab    = (float*)w; w += 11 * 256 * 4;
    float* self0_tab = (float*)w; w += 11 * 256 * 4;
    float* msg0_tab  = (float*)w; w += 55 * 256 * 4;
    float* bondtab   = (float*)w; w += 2 * 5 * 256 * 4;
    u16* BtL1  = (u16*)w; w += 512 * 256 * 2;
    u16* BtL2  = (u16*)w; w += 512 * 256 * 2;
    u16* Bt3   = (u16*)w; w += 384 * 256 * 2;
    u16* BtW2  = (u16*)w; w += 128 * 128 * 2;
    u16* BtCP2 = (u16*)w; w += 128 * 128 * 2;
    float* bias512  = (float*)w; w += 2 * 512 * 4;
    float* biasPost = (float*)w; w += 384 * 4;

    // ---- setup ----
    k_type_mlp<<<1, 256, 0, stream>>>(atom_emb, vp_w1, vp_b1, vp_w2, vp_b2, pv_tab, vl_tab, h0_tab);
    k_tables<<<76, 256, 0, stream>>>(bond_emb, gnn_wself, gnn_bself, gnn_wmsg, gnn_bmsg,
                                     h0_tab, self0_tab, msg0_tab, bondtab);
    k_wtrans<<<1664, 256, 0, stream>>>(gnn_wmsg, gnn_wself, bc_w1, cp_w1, bc_w2, cp_w2,
                                       BtL1, BtL2, Bt3, BtW2, BtCP2);
    k_setup_bias<<<6, 256, 0, stream>>>(gnn_bself, bc_b1, cp_b1, bias512, biasPost);
    k_node_init<<<(N_NODES + 255) / 256, 256, 0, stream>>>(x, pv_tab, vl_tab, types, pvarr, degree, vl_out);
    k_edge_deg<<<(N_EDGES + 255) / 256, 256, 0, stream>>>(ei, degree);
    int nb = (N_NODES + SCAN_B - 1) / SCAN_B;
    k_scan1<<<nb, SCAN_B, 0, stream>>>(degree, offsets, bsum);
    k_scan2<<<1, 128, 0, stream>>>(bsum, bbase, nb);
    k_scan3<<<nb, SCAN_B, 0, stream>>>(offsets, bbase, cursor);
    k_csr_fill<<<(N_EDGES + 255) / 256, 256, 0, stream>>>(ei, edge_attr, types, cursor, csr);
    k_agg0<<<N_NODES / 4, 256, 0, stream>>>(offsets, degree, types, self0_tab, msg0_tab, csr, h_bf);

    // ---- GNN layers 1,2 ----
    const int MT = M_PAD / 128;           // 782
    const int QB = (MT + 7) / 8;          // 98
    for (int l = 1; l <= 2; ++l) {
        const u16* BtL = (l == 1) ? BtL1 : BtL2;
        k_gemm_dual<<<QB * 32, 256, 0, stream>>>(h_bf, BtL, bias512 + (size_t)(l - 1) * 512,
                                                 hm_bf, hs_bf, N_NODES, MT);
        k_agg12<<<N_NODES / 4, 256, 0, stream>>>(offsets, degree, hs_bf, hm_bf,
                                                 bondtab + (size_t)(l - 1) * 5 * 256, csr, h_bf);
    }

    // ---- damp ----
    k_damp<<<(N_NODES * 64 + 255) / 256, 256, 0, stream>>>(h_bf, degree, pvarr, h_out, hd_bf, vi_out);

    // ---- uv + cp1 fused; then cp2 ----
    k_gemm_post<<<QB * 24, 256, 0, stream>>>(hd_bf, Bt3, biasPost, uv_bf, cp1_bf, N_NODES, MT);
    k_gemm_k128<<<MT, 256, 0, stream>>>(cp1_bf, BtCP2, cp_b2, cp_out, 32, N_NODES, 32, 0);

    // ---- bond chain (single pass) ----
    k_bond_t1<<<(N_EDGES * 32 + 255) / 256, 256, 0, stream>>>(ei, pvarr, uv_bf, bc_w1, T1);
    k_gemm_k128<<<E_PAD / 128, 256, 0, stream>>>(T1, BtW2, bc_b2, T2, 64, N_EDGES, 64, 3);
    k_bond_out<<<(N_EDGES + 255) / 256, 256, 0, stream>>>(T2, ei, types, pvarr, bc_w3, bc_b3, bl_out);
}

// Round 6
// 664.514 us; speedup vs baseline: 2.6527x; 1.1133x over previous
//
#include <hip/hip_runtime.h>

#define N_NODES 100000
#define N_EDGES 300000
#define M_PAD   100096   // 782*128
#define E_PAD   300032   // 2344*128

typedef unsigned short u16;
typedef short bf16x8 __attribute__((ext_vector_type(8)));
typedef float f32x4  __attribute__((ext_vector_type(4)));

__device__ __forceinline__ float bf2f(u16 u) {
    unsigned x = ((unsigned)u) << 16;
    return __builtin_bit_cast(float, x);
}
__device__ __forceinline__ u16 f2bf(float f) {
    unsigned u = __builtin_bit_cast(unsigned, f);
    unsigned r = (u + 0x7FFF + ((u >> 16) & 1)) >> 16;
    return (u16)r;
}

// ---------------- output layout (floats) ----------------
#define H_OFF   0
#define CP_OFF  25600000
#define VL_OFF  28800000
#define BL_OFF  29600000
#define VI_OFF  30800000

#define GLL(gp, lp) __builtin_amdgcn_global_load_lds( \
    (const __attribute__((address_space(1))) unsigned int*)(gp), \
    (__attribute__((address_space(3))) unsigned int*)(lp), 16, 0, 0)

// ============ per-atom-type valence MLP + h0 rows ============
__global__ void k_type_mlp(const float* __restrict__ atom_emb,
                           const float* __restrict__ vp_w1, const float* __restrict__ vp_b1,
                           const float* __restrict__ vp_w2, const float* __restrict__ vp_b2,
                           int* __restrict__ pv_tab, float* __restrict__ vl_tab,
                           float* __restrict__ h0_tab)
{
    int tid = threadIdx.x;
    for (int i = tid; i < 11 * 256; i += 256) h0_tab[i] = 0.f;
    __syncthreads();
    if (tid < 11) {
        int t = tid;
        const float* ae = atom_emb + t * 64;
        float lg[8];
        #pragma unroll
        for (int c = 0; c < 8; ++c) lg[c] = vp_b2[c];
        for (int j = 0; j < 32; ++j) {
            float z = vp_b1[j];
            for (int d = 0; d < 64; ++d) z += ae[d] * vp_w1[d * 32 + j];
            z = fmaxf(z, 0.f);
            #pragma unroll
            for (int c = 0; c < 8; ++c) lg[c] += z * vp_w2[j * 8 + c];
        }
        int best = 0;
        #pragma unroll
        for (int c = 1; c < 8; ++c) if (lg[c] > lg[best]) best = c;
        pv_tab[t] = best + 1;
        for (int c = 0; c < 8; ++c) vl_tab[t * 8 + c] = lg[c];
        float* h0 = h0_tab + t * 256;
        for (int d = 0; d < 64; ++d) h0[d] = ae[d];
        h0[64 + best] = 1.f;
    }
}

// ============ layer-0 tables + bond tables for layers 1,2 ============
__global__ void k_tables(const float* __restrict__ bond_emb,
                         const float* __restrict__ gnn_wself, const float* __restrict__ gnn_bself,
                         const float* __restrict__ gnn_wmsg, const float* __restrict__ gnn_bmsg,
                         const float* __restrict__ h0_tab,
                         float* __restrict__ self0_tab, float* __restrict__ msg0_tab,
                         float* __restrict__ bondtab)
{
    int b = blockIdx.x, c = threadIdx.x;
    if (b < 11) {
        int t = b;
        const float* h0 = h0_tab + t * 256;
        float acc = gnn_bself[c];
        for (int k = 0; k < 256; ++k) acc += h0[k] * gnn_wself[k * 256 + c];
        self0_tab[t * 256 + c] = acc;
    } else if (b < 66) {
        int idx = b - 11; int t = idx / 5, bb = idx % 5;
        const float* h0 = h0_tab + t * 256;
        float acc = gnn_bmsg[c];
        for (int k = 0; k < 256; ++k) acc += h0[k] * gnn_wmsg[k * 256 + c];
        const float* be = bond_emb + bb * 64;
        for (int k = 0; k < 64; ++k) acc += be[k] * gnn_wmsg[(256 + k) * 256 + c];
        msg0_tab[idx * 256 + c] = fmaxf(acc, 0.f);
    } else {
        int idx = b - 66; int l = idx / 5 + 1, bb = idx % 5;
        const float* w = gnn_wmsg + (size_t)l * 320 * 256;
        const float* be = bond_emb + bb * 64;
        float acc = gnn_bmsg[l * 256 + c];
        for (int k = 0; k < 64; ++k) acc += be[k] * w[(256 + k) * 256 + c];
        bondtab[(l - 1) * 5 * 256 + bb * 256 + c] = acc;
    }
}

// ============ bf16-transposed weight tables ============
__global__ void k_wtrans(const float* __restrict__ wmsg, const float* __restrict__ wself,
                         const float* __restrict__ bcw1, const float* __restrict__ cpw1,
                         const float* __restrict__ bcw2, const float* __restrict__ cpw2,
                         u16* __restrict__ BtL1, u16* __restrict__ BtL2, u16* __restrict__ Bt3,
                         u16* __restrict__ BtW2, u16* __restrict__ BtCP2)
{
    int b = blockIdx.x, k = threadIdx.x;
    if (b < 512) {
        int n = b;
        float v = (n < 256) ? wmsg[(size_t)1 * 320 * 256 + (size_t)k * 256 + n]
                            : wself[(size_t)1 * 256 * 256 + (size_t)k * 256 + (n - 256)];
        BtL1[n * 256 + k] = f2bf(v);
    } else if (b < 1024) {
        int n = b - 512;
        float v = (n < 256) ? wmsg[(size_t)2 * 320 * 256 + (size_t)k * 256 + n]
                            : wself[(size_t)2 * 256 * 256 + (size_t)k * 256 + (n - 256)];
        BtL2[n * 256 + k] = f2bf(v);
    } else if (b < 1408) {
        int n = b - 1024;
        float v;
        if (n < 128)      v = bcw1[k * 128 + n];
        else if (n < 256) v = bcw1[(256 + k) * 128 + (n - 128)];
        else              v = cpw1[k * 128 + (n - 256)];
        Bt3[n * 256 + k] = f2bf(v);
    } else if (b < 1536) {
        int n = b - 1408;
        if (k < 128) BtW2[n * 128 + k] = f2bf(n < 64 ? bcw2[k * 64 + n] : 0.f);
    } else {
        int n = b - 1536;
        if (k < 128) BtCP2[n * 128 + k] = f2bf(n < 32 ? cpw2[k * 32 + n] : 0.f);
    }
}

__global__ void k_setup_bias(const float* __restrict__ bself, const float* __restrict__ bcb1,
                             const float* __restrict__ cpb1,
                             float* __restrict__ bias512, float* __restrict__ biasPost)
{
    int i = blockIdx.x * 256 + threadIdx.x;
    if (i < 1024) {
        int l = i >> 9, c = i & 511;
        bias512[l * 512 + c] = (c < 256) ? 0.f : bself[(l + 1) * 256 + (c - 256)];
    } else if (i < 1408) {
        int c = i - 1024;
        biasPost[c] = (c < 128) ? bcb1[c] : ((c < 256) ? 0.f : cpb1[c - 256]);
    }
}

// ============ node init ============
__global__ void k_node_init(const float* __restrict__ x, const int* __restrict__ pv_tab,
                            const float* __restrict__ vl_tab,
                            int* __restrict__ types, int* __restrict__ pvarr,
                            int* __restrict__ degree, float* __restrict__ vl_out)
{
    int i = blockIdx.x * blockDim.x + threadIdx.x;
    if (i >= N_NODES) return;
    int t = (int)x[i * 16];
    t = min(max(t, 0), 10);
    types[i] = t;
    pvarr[i] = pv_tab[t];
    degree[i] = 0;
    float4 v0 = *(const float4*)&vl_tab[t * 8];
    float4 v1 = *(const float4*)&vl_tab[t * 8 + 4];
    *(float4*)&vl_out[i * 8]     = v0;
    *(float4*)&vl_out[i * 8 + 4] = v1;
}

__global__ void k_edge_deg(const int* __restrict__ ei, int* __restrict__ degree)
{
    int e = blockIdx.x * blockDim.x + threadIdx.x;
    if (e >= N_EDGES) return;
    atomicAdd(&degree[ei[e]], 1);
}

// ============ scan ============
#define SCAN_B 1024
__global__ void k_scan1(const int* __restrict__ degree, int* __restrict__ part, int* __restrict__ bsum)
{
    __shared__ int s[SCAN_B];
    int tid = threadIdx.x;
    int i = blockIdx.x * SCAN_B + tid;
    int v = (i < N_NODES) ? degree[i] : 0;
    s[tid] = v; __syncthreads();
    for (int off = 1; off < SCAN_B; off <<= 1) {
        int t = (tid >= off) ? s[tid - off] : 0;
        __syncthreads();
        s[tid] += t;
        __syncthreads();
    }
    if (i < N_NODES) part[i] = s[tid] - v;
    if (tid == SCAN_B - 1) bsum[blockIdx.x] = s[tid];
}

__global__ void k_scan2(const int* __restrict__ bsum, int* __restrict__ bbase, int nb)
{
    __shared__ int s[128];
    int tid = threadIdx.x;
    int v = (tid < nb) ? bsum[tid] : 0;
    s[tid] = v; __syncthreads();
    for (int off = 1; off < 128; off <<= 1) {
        int t = (tid >= off) ? s[tid - off] : 0;
        __syncthreads();
        s[tid] += t;
        __syncthreads();
    }
    bbase[tid] = s[tid] - v;
}

__global__ void k_scan3(int* __restrict__ part, const int* __restrict__ bbase, int* __restrict__ cursor)
{
    int i = blockIdx.x * SCAN_B + threadIdx.x;
    if (i >= N_NODES) return;
    int o = part[i] + bbase[blockIdx.x];
    part[i] = o;
    cursor[i] = o;
}

// ============ CSR fill (+ row/eid side arrays for the bond pass) ============
__global__ void k_csr_fill(const int* __restrict__ ei, const float* __restrict__ edge_attr,
                           const int* __restrict__ types, int* __restrict__ cursor,
                           int* __restrict__ csr, int* __restrict__ rowcsr, int* __restrict__ eidarr)
{
    int e = blockIdx.x * blockDim.x + threadIdx.x;
    if (e >= N_EDGES) return;
    int row = ei[e], col = ei[N_EDGES + e];
    int bt = (int)edge_attr[e * 4];
    bt = min(max(bt, 0), 4);
    int pos = atomicAdd(&cursor[row], 1);
    csr[pos] = col | (bt << 20) | (types[col] << 24);
    rowcsr[pos] = row;
    eidarr[pos] = e;
}

// ============ layer-0 aggregation (tables) -> h bf16 ============
__global__ __launch_bounds__(256) void k_agg0(const int* __restrict__ offsets, const int* __restrict__ degree,
                       const int* __restrict__ types,
                       const float* __restrict__ self0_tab, const float* __restrict__ msg0_tab,
                       const int* __restrict__ csr, u16* __restrict__ h)
{
    int wid = threadIdx.x >> 6, lane = threadIdx.x & 63;
    int node = blockIdx.x * 4 + wid;
    if (node >= N_NODES) return;
    int t = types[node];
    float4 acc = *(const float4*)&self0_tab[t * 256 + lane * 4];
    int start = offsets[node], deg = degree[node];
    for (int j = 0; j < deg; ++j) {
        int p = csr[start + j];
        int combo = ((p >> 24) & 0xF) * 5 + ((p >> 20) & 7);
        float4 m = *(const float4*)&msg0_tab[combo * 256 + lane * 4];
        acc.x += m.x; acc.y += m.y; acc.z += m.z; acc.w += m.w;
    }
    ushort4 r;
    r.x = f2bf(fmaxf(acc.x, 0.f)); r.y = f2bf(fmaxf(acc.y, 0.f));
    r.z = f2bf(fmaxf(acc.z, 0.f)); r.w = f2bf(fmaxf(acc.w, 0.f));
    *(ushort4*)&h[(size_t)node * 256 + lane * 4] = r;
}

// ============ layers 1,2 aggregation; final layer fuses damp/viol/h_out ============
__global__ __launch_bounds__(256) void k_agg12(const int* __restrict__ offsets, const int* __restrict__ degree,
                        const u16* __restrict__ hs, const u16* __restrict__ hm,
                        const float* __restrict__ bondtab, const int* __restrict__ csr,
                        u16* __restrict__ h, int final_layer, const int* __restrict__ pvarr,
                        float* __restrict__ h_out, u16* __restrict__ hd_bf, float* __restrict__ viol_out)
{
    int wid = threadIdx.x >> 6, lane = threadIdx.x & 63;
    int node = blockIdx.x * 4 + wid;
    if (node >= N_NODES) return;
    ushort4 s4 = *(const ushort4*)&hs[(size_t)node * 256 + lane * 4];
    float ax = bf2f(s4.x), ay = bf2f(s4.y), az = bf2f(s4.z), aw = bf2f(s4.w);
    int start = offsets[node], deg = degree[node];
    for (int j = 0; j < deg; ++j) {
        int p = csr[start + j];
        int c = p & 0xFFFFF;
        int bt = (p >> 20) & 7;
        ushort4 m4 = *(const ushort4*)&hm[(size_t)c * 256 + lane * 4];
        float4 bb = *(const float4*)&bondtab[bt * 256 + lane * 4];
        ax += fmaxf(bf2f(m4.x) + bb.x, 0.f);
        ay += fmaxf(bf2f(m4.y) + bb.y, 0.f);
        az += fmaxf(bf2f(m4.z) + bb.z, 0.f);
        aw += fmaxf(bf2f(m4.w) + bb.w, 0.f);
    }
    ax = fmaxf(ax, 0.f); ay = fmaxf(ay, 0.f); az = fmaxf(az, 0.f); aw = fmaxf(aw, 0.f);
    if (!final_layer) {
        ushort4 r;
        r.x = f2bf(ax); r.y = f2bf(ay); r.z = f2bf(az); r.w = f2bf(aw);
        *(ushort4*)&h[(size_t)node * 256 + lane * 4] = r;
    } else {
        float viol = fmaxf((float)deg - (float)pvarr[node], 0.f);
        float s = 1.f / (1.f + viol);
        ax *= s; ay *= s; az *= s; aw *= s;
        float4 v = make_float4(ax, ay, az, aw);
        *(float4*)&h_out[(size_t)node * 256 + lane * 4] = v;
        ushort4 r;
        r.x = f2bf(ax); r.y = f2bf(ay); r.z = f2bf(az); r.w = f2bf(aw);
        *(ushort4*)&hd_bf[(size_t)node * 256 + lane * 4] = r;
        if (lane == 0) viol_out[node] = viol;
    }
}

// ================== layer GEMM, 2-barrier 16KB-LDS + XCD swizzle ==================
__global__ __launch_bounds__(256) void k_gemm_dual(
    const u16* __restrict__ A, const u16* __restrict__ Bt,
    const float* __restrict__ bias512,
    u16* __restrict__ Dm, u16* __restrict__ Ds, int M, int MT)
{
    __shared__ u16 As[128 * 32];
    __shared__ u16 Bs[128 * 32];
    int b = blockIdx.x;
    int rsub = b & 31;
    int nt = rsub >> 3, m8 = rsub & 7;
    int mt = (b >> 5) * 8 + m8;
    if (mt >= MT) return;
    int bm = mt * 128, bn = nt * 128;

    int t = threadIdx.x;
    int lane = t & 63, w = t >> 6;
    int wm = w & 1, wn = w >> 1;
    f32x4 zero = {0.f, 0.f, 0.f, 0.f};
    f32x4 acc[4][4];
    #pragma unroll
    for (int i = 0; i < 4; ++i)
        #pragma unroll
        for (int j = 0; j < 4; ++j) acc[i][j] = zero;

    int arow = t >> 2, acol = (t & 3) * 8;
    const u16* Ag = A + (size_t)(bm + arow) * 256 + acol;
    const u16* Bg = Bt + (size_t)(bn + arow) * 256 + acol;
    u16* Asp = As + t * 8;
    u16* Bsp = Bs + t * 8;
    int q = lane >> 4, r = lane & 15;

    for (int k0 = 0; k0 < 256; k0 += 32) {
        __syncthreads();
        GLL(Ag + k0,            Asp);
        GLL(Ag + 64 * 256 + k0, Asp + 2048);
        GLL(Bg + k0,            Bsp);
        GLL(Bg + 64 * 256 + k0, Bsp + 2048);
        __syncthreads();
        bf16x8 af[4], bfr[4];
        #pragma unroll
        for (int i = 0; i < 4; ++i)
            af[i] = *(const bf16x8*)&As[(wm * 64 + i * 16 + r) * 32 + q * 8];
        #pragma unroll
        for (int j = 0; j < 4; ++j)
            bfr[j] = *(const bf16x8*)&Bs[(wn * 64 + j * 16 + r) * 32 + q * 8];
        #pragma unroll
        for (int i = 0; i < 4; ++i)
            #pragma unroll
            for (int j = 0; j < 4; ++j)
                acc[i][j] = __builtin_amdgcn_mfma_f32_16x16x32_bf16(af[i], bfr[j], acc[i][j], 0, 0, 0);
    }
    #pragma unroll
    for (int i = 0; i < 4; ++i) {
        int rowb = bm + wm * 64 + i * 16 + q * 4;
        #pragma unroll
        for (int j = 0; j < 4; ++j) {
            int colg = bn + wn * 64 + j * 16 + r;
            float bv = bias512[colg];
            u16* D = (colg < 256) ? Dm : Ds;
            int col = colg & 255;
            #pragma unroll
            for (int rr = 0; rr < 4; ++rr) {
                int rowg = rowb + rr;
                if (rowg < M) D[(size_t)rowg * 256 + col] = f2bf(acc[i][j][rr] + bv);
            }
        }
    }
}

// ================== post GEMM (N=384: uv 256 bf16 + cp1 128 bf16-relu), swizzled ==================
__global__ __launch_bounds__(256) void k_gemm_post(
    const u16* __restrict__ A, const u16* __restrict__ Bt3,
    const float* __restrict__ biasPost,
    u16* __restrict__ UV, u16* __restrict__ CP1, int M, int MT)
{
    __shared__ u16 As[128 * 32];
    __shared__ u16 Bs[128 * 32];
    int b = blockIdx.x;
    int rsub = b % 24;
    int nt = rsub >> 3, m8 = rsub & 7;
    int mt = (b / 24) * 8 + m8;
    if (mt >= MT) return;
    int bm = mt * 128, bn = nt * 128;

    int t = threadIdx.x;
    int lane = t & 63, w = t >> 6;
    int wm = w & 1, wn = w >> 1;
    f32x4 zero = {0.f, 0.f, 0.f, 0.f};
    f32x4 acc[4][4];
    #pragma unroll
    for (int i = 0; i < 4; ++i)
        #pragma unroll
        for (int j = 0; j < 4; ++j) acc[i][j] = zero;

    int arow = t >> 2, acol = (t & 3) * 8;
    const u16* Ag = A + (size_t)(bm + arow) * 256 + acol;
    const u16* Bg = Bt3 + (size_t)(bn + arow) * 256 + acol;
    u16* Asp = As + t * 8;
    u16* Bsp = Bs + t * 8;
    int q = lane >> 4, r = lane & 15;

    for (int k0 = 0; k0 < 256; k0 += 32) {
        __syncthreads();
        GLL(Ag + k0,            Asp);
        GLL(Ag + 64 * 256 + k0, Asp + 2048);
        GLL(Bg + k0,            Bsp);
        GLL(Bg + 64 * 256 + k0, Bsp + 2048);
        __syncthreads();
        bf16x8 af[4], bfr[4];
        #pragma unroll
        for (int i = 0; i < 4; ++i)
            af[i] = *(const bf16x8*)&As[(wm * 64 + i * 16 + r) * 32 + q * 8];
        #pragma unroll
        for (int j = 0; j < 4; ++j)
            bfr[j] = *(const bf16x8*)&Bs[(wn * 64 + j * 16 + r) * 32 + q * 8];
        #pragma unroll
        for (int i = 0; i < 4; ++i)
            #pragma unroll
            for (int j = 0; j < 4; ++j)
                acc[i][j] = __builtin_amdgcn_mfma_f32_16x16x32_bf16(af[i], bfr[j], acc[i][j], 0, 0, 0);
    }
    #pragma unroll
    for (int i = 0; i < 4; ++i) {
        int rowb = bm + wm * 64 + i * 16 + q * 4;
        #pragma unroll
        for (int j = 0; j < 4; ++j) {
            int coll = wn * 64 + j * 16 + r;
            float bv = biasPost[bn + coll];
            #pragma unroll
            for (int rr = 0; rr < 4; ++rr) {
                int rowg = rowb + rr;
                if (rowg < M) {
                    float val = acc[i][j][rr] + bv;
                    if (nt < 2) UV[(size_t)rowg * 256 + bn + coll] = f2bf(val);
                    else        CP1[(size_t)rowg * 128 + coll] = f2bf(fmaxf(val, 0.f));
                }
            }
        }
    }
}

// ================== small K=128 MFMA GEMM (cp2 only) ==================
__global__ __launch_bounds__(256) void k_gemm_k128(
    const u16* __restrict__ A, const u16* __restrict__ Bt,
    const float* __restrict__ bias, float* __restrict__ C,
    int ldc, int M, int N)
{
    __shared__ u16 As[4096];
    __shared__ u16 Bs[4096];
    int t = threadIdx.x;
    int lane = t & 63, w = t >> 6;
    int wm = w & 1, wn = w >> 1;
    int bm = blockIdx.x * 128;
    int arow = t >> 2, acol = (t & 3) * 8;
    int q = lane >> 4, r = lane & 15;
    const u16* Ag = A + (size_t)(bm + arow) * 128 + acol;
    const u16* Bg = Bt + (size_t)arow * 128 + acol;
    f32x4 zero = {0.f, 0.f, 0.f, 0.f};
    f32x4 acc[4][4];
    #pragma unroll
    for (int i = 0; i < 4; ++i)
        #pragma unroll
        for (int j = 0; j < 4; ++j) acc[i][j] = zero;

    for (int kc = 0; kc < 4; ++kc) {
        __syncthreads();
        GLL(Ag + kc * 32,            As + t * 8);
        GLL(Ag + 64 * 128 + kc * 32, As + 2048 + t * 8);
        GLL(Bg + kc * 32,            Bs + t * 8);
        GLL(Bg + 64 * 128 + kc * 32, Bs + 2048 + t * 8);
        __syncthreads();
        bf16x8 af[4], bfr[4];
        #pragma unroll
        for (int i = 0; i < 4; ++i)
            af[i] = *(const bf16x8*)&As[(wm * 64 + i * 16 + r) * 32 + q * 8];
        #pragma unroll
        for (int j = 0; j < 4; ++j)
            bfr[j] = *(const bf16x8*)&Bs[(wn * 64 + j * 16 + r) * 32 + q * 8];
        #pragma unroll
        for (int i = 0; i < 4; ++i)
            #pragma unroll
            for (int j = 0; j < 4; ++j)
                acc[i][j] = __builtin_amdgcn_mfma_f32_16x16x32_bf16(af[i], bfr[j], acc[i][j], 0, 0, 0);
    }
    #pragma unroll
    for (int i = 0; i < 4; ++i) {
        int rowb = bm + wm * 64 + i * 16 + q * 4;
        #pragma unroll
        for (int j = 0; j < 4; ++j) {
            int colg = wn * 64 + j * 16 + r;
            if (colg >= N) continue;
            float bv = bias[colg];
            #pragma unroll
            for (int rr = 0; rr < 4; ++rr) {
                int rowg = rowb + rr;
                if (rowg < M) C[(size_t)rowg * ldc + colg] = acc[i][j][rr] + bv;
            }
        }
    }
}

// ================== fused bond kernel ==================
// Per block: 128 CSR-ordered edges. Stage1: T1 tile (relu(u[row]+v[col]+pv terms)) in LDS.
// Stage2: MFMA T1[128,128] x W2t -> T2 (cols<64), bias+relu into LDS (f32).
// Stage3: per-row dot with W3 + penalties -> bl_out[eid].
__global__ __launch_bounds__(256) void k_bond_fused(
    const int* __restrict__ csr, const int* __restrict__ rowcsr, const int* __restrict__ eidarr,
    const int* __restrict__ types, const int* __restrict__ pvarr, const int* __restrict__ pv_tab,
    const u16* __restrict__ uv, const float* __restrict__ bc_w1,
    const u16* __restrict__ BtW2, const float* __restrict__ bc_b2,
    const float* __restrict__ bc_w3, const float* __restrict__ bc_b3,
    float* __restrict__ bl_out)
{
    __shared__ u16 T1s[16384];     // 32 KB: 4 chunks x [128 rows][32 k]; reused as f32 T2 [128][64]
    __shared__ u16 Bs[16384];      // 32 KB: 4 chunks x [128 cols][32 k]
    __shared__ float w5s[128], w6s[128], W3s[256], b2s[64], b3s[4];
    __shared__ int pvts[16];

    int t = threadIdx.x;
    int p0 = blockIdx.x * 128;

    // ---- preload small tables + Bs (via GLL) ----
    if (t < 128) { w5s[t] = bc_w1[512 * 128 + t]; w6s[t] = bc_w1[513 * 128 + t]; }
    if (t < 256) W3s[t] = bc_w3[t];
    if (t < 64) b2s[t] = bc_b2[t];
    if (t < 4)  b3s[t] = bc_b3[t];
    if (t < 11) pvts[t] = pv_tab[t];
    #pragma unroll
    for (int c = 0; c < 4; ++c) {
        GLL(BtW2 + (size_t)(t >> 2) * 128 + c * 32 + (t & 3) * 8,        Bs + c * 4096 + t * 8);
        GLL(BtW2 + (size_t)(64 + (t >> 2)) * 128 + c * 32 + (t & 3) * 8, Bs + c * 4096 + 2048 + t * 8);
    }

    // ---- stage 1: build T1 tile (2 threads per edge row, 64 cols each) ----
    int l = t >> 1;            // local row 0..127
    int half = t & 1;          // which 64-col half
    int pos = p0 + l;
    int prow = 0, pk = 0;
    if (pos < N_EDGES) { prow = rowcsr[pos]; pk = csr[pos]; }
    int pcol = pk & 0xFFFFF;
    float pvr = (float)pvarr[prow];
    float pvc = (float)pvts[(pk >> 24) & 0xF];
    __syncthreads();   // w5s/w6s ready

    const u16* up = uv + (size_t)prow * 256 + half * 64;
    const u16* vp = uv + (size_t)pcol * 256 + 128 + half * 64;
    #pragma unroll
    for (int j = 0; j < 8; ++j) {
        int c = half * 64 + j * 8;
        ushort4 ua = *(const ushort4*)(up + j * 8);
        ushort4 ub = *(const ushort4*)(up + j * 8 + 4);
        ushort4 va = *(const ushort4*)(vp + j * 8);
        ushort4 vb = *(const ushort4*)(vp + j * 8 + 4);
        int chunk = c >> 5, kk = c & 31;
        u16* dst = T1s + chunk * 4096 + l * 32 + kk;
        dst[0] = f2bf(fmaxf(bf2f(ua.x) + bf2f(va.x) + pvr * w5s[c+0] + pvc * w6s[c+0], 0.f));
        dst[1] = f2bf(fmaxf(bf2f(ua.y) + bf2f(va.y) + pvr * w5s[c+1] + pvc * w6s[c+1], 0.f));
        dst[2] = f2bf(fmaxf(bf2f(ua.z) + bf2f(va.z) + pvr * w5s[c+2] + pvc * w6s[c+2], 0.f));
        dst[3] = f2bf(fmaxf(bf2f(ua.w) + bf2f(va.w) + pvr * w5s[c+3] + pvc * w6s[c+3], 0.f));
        dst[4] = f2bf(fmaxf(bf2f(ub.x) + bf2f(vb.x) + pvr * w5s[c+4] + pvc * w6s[c+4], 0.f));
        dst[5] = f2bf(fmaxf(bf2f(ub.y) + bf2f(vb.y) + pvr * w5s[c+5] + pvc * w6s[c+5], 0.f));
        dst[6] = f2bf(fmaxf(bf2f(ub.z) + bf2f(vb.z) + pvr * w5s[c+6] + pvc * w6s[c+6], 0.f));
        dst[7] = f2bf(fmaxf(bf2f(ub.w) + bf2f(vb.w) + pvr * w5s[c+7] + pvc * w6s[c+7], 0.f));
    }
    __syncthreads();   // T1s + Bs (GLL drained by barrier) ready

    // ---- stage 2: MFMA T1[128,128] x W2t[128,128] ----
    int lane = t & 63, w = t >> 6;
    int wm = w & 1, wn = w >> 1;
    int q = lane >> 4, r = lane & 15;
    f32x4 zero = {0.f, 0.f, 0.f, 0.f};
    f32x4 acc[4][4];
    #pragma unroll
    for (int i = 0; i < 4; ++i)
        #pragma unroll
        for (int j = 0; j < 4; ++j) acc[i][j] = zero;
    #pragma unroll
    for (int c = 0; c < 4; ++c) {
        bf16x8 af[4], bfr[4];
        #pragma unroll
        for (int i = 0; i < 4; ++i)
            af[i] = *(const bf16x8*)&T1s[c * 4096 + (wm * 64 + i * 16 + r) * 32 + q * 8];
        #pragma unroll
        for (int j = 0; j < 4; ++j)
            bfr[j] = *(const bf16x8*)&Bs[c * 4096 + (wn * 64 + j * 16 + r) * 32 + q * 8];
        #pragma unroll
        for (int i = 0; i < 4; ++i)
            #pragma unroll
            for (int j = 0; j < 4; ++j)
                acc[i][j] = __builtin_amdgcn_mfma_f32_16x16x32_bf16(af[i], bfr[j], acc[i][j], 0, 0, 0);
    }
    __syncthreads();   // all T1s reads done; reuse as f32 T2

    float* T2f = (float*)T1s;   // [128][64]
    if (wn == 0) {
        #pragma unroll
        for (int i = 0; i < 4; ++i) {
            int row = wm * 64 + i * 16 + q * 4;
            #pragma unroll
            for (int j = 0; j < 4; ++j) {
                int col = j * 16 + r;
                float bv = b2s[col];
                #pragma unroll
                for (int rr = 0; rr < 4; ++rr)
                    T2f[(row + rr) * 64 + col] = fmaxf(acc[i][j][rr] + bv, 0.f);
            }
        }
    }
    __syncthreads();

    // ---- stage 3: per-row W3 dot + penalties ----
    if (t < 128) {
        int pos3 = p0 + t;
        if (pos3 < N_EDGES) {
            float a0 = b3s[0], a1 = b3s[1], a2 = b3s[2], a3 = b3s[3];
            const float* trow = &T2f[t * 64];
            #pragma unroll 8
            for (int kk = 0; kk < 64; ++kk) {
                int k = (kk + t) & 63;           // rotate start: spread banks across lanes
                float tv = trow[k];
                a0 += tv * W3s[k * 4 + 0];
                a1 += tv * W3s[k * 4 + 1];
                a2 += tv * W3s[k * 4 + 2];
                a3 += tv * W3s[k * 4 + 3];
            }
            int prow3 = rowcsr[pos3];
            int pk3 = csr[pos3];
            int tc = (pk3 >> 24) & 0xF;
            int tr = types[prow3];
            int pr = pvarr[prow3];
            int pc = pvts[tc];
            float halogen = (tr == 4 || tr == 5 || tc == 4 || tc == 5) ? 1.f : 0.f;
            float l1 = (pr <= 1 || pc <= 1) ? 1.f : 0.f;
            float l2 = (pr <= 2 || pc <= 2) ? 1.f : 0.f;
            float pen13 = -100.f * halogen - 50.f * l1;
            a1 += pen13;
            a3 += pen13;
            a2 += pen13 - 50.f * l2;
            int eid = eidarr[pos3];
            *(float4*)&bl_out[(size_t)eid * 4] = make_float4(a0, a1, a2, a3);
        }
    }
}

// ================================================================
extern "C" void kernel_launch(void* const* d_in, const int* in_sizes, int n_in,
                              void* d_out, int out_size, void* d_ws, size_t ws_size,
                              hipStream_t stream)
{
    const float* x          = (const float*)d_in[0];
    const float* edge_attr  = (const float*)d_in[1];
    const float* atom_emb   = (const float*)d_in[2];
    const float* bond_emb   = (const float*)d_in[3];
    const float* vp_w1      = (const float*)d_in[4];
    const float* vp_b1      = (const float*)d_in[5];
    const float* vp_w2      = (const float*)d_in[6];
    const float* vp_b2      = (const float*)d_in[7];
    const float* gnn_wself  = (const float*)d_in[8];
    const float* gnn_bself  = (const float*)d_in[9];
    const float* gnn_wmsg   = (const float*)d_in[10];
    const float* gnn_bmsg   = (const float*)d_in[11];
    const float* bc_w1      = (const float*)d_in[12];
    const float* bc_b1      = (const float*)d_in[13];
    const float* bc_w2      = (const float*)d_in[14];
    const float* bc_b2      = (const float*)d_in[15];
    const float* bc_w3      = (const float*)d_in[16];
    const float* bc_b3      = (const float*)d_in[17];
    const float* cp_w1      = (const float*)d_in[18];
    const float* cp_b1      = (const float*)d_in[19];
    const float* cp_w2      = (const float*)d_in[20];
    const float* cp_b2      = (const float*)d_in[21];
    const int*   ei         = (const int*)d_in[22];

    float* out    = (float*)d_out;
    float* h_out  = out + H_OFF;
    float* cp_out = out + CP_OFF;
    float* vl_out = out + VL_OFF;
    float* bl_out = out + BL_OFF;
    float* vi_out = out + VI_OFF;

    // ---- workspace layout ----
    char* base = (char*)d_ws;
    const size_t S = (size_t)M_PAD * 256 * 2;   // 51,249,152 B
    u16* h_bf  = (u16*)(base + 0 * S);           // R0: h ; later uv
    u16* uv_bf = (u16*)(base + 0 * S);
    u16* hm_bf = (u16*)(base + 1 * S);           // R1: hm
    u16* hs_bf = (u16*)(base + 2 * S);           // R2: hs
    u16* hd_bf = (u16*)(base + 3 * S);           // R3: damped h bf16
    u16* cp1_bf= (u16*)(base + 4 * S);           // R4: [M_PAD][128] bf16
    char* w    = base + 4 * S + (size_t)M_PAD * 128 * 2;
    int* degree  = (int*)w; w += (size_t)N_NODES * 4;
    int* offsets = (int*)w; w += (size_t)N_NODES * 4;
    int* cursor  = (int*)w; w += (size_t)N_NODES * 4;
    int* types   = (int*)w; w += (size_t)N_NODES * 4;
    int* pvarr   = (int*)w; w += (size_t)N_NODES * 4;
    int* csr     = (int*)w; w += (size_t)E_PAD * 4;
    int* rowcsr  = (int*)w; w += (size_t)E_PAD * 4;
    int* eidarr  = (int*)w; w += (size_t)E_PAD * 4;
    int* bsum    = (int*)w; w += 4096;
    int* bbase   = (int*)w; w += 4096;
    int* pv_tab  = (int*)w; w += 1024;
    float* vl_tab    = (float*)w; w += 2048;
    float* h0_tab    = (float*)w; w += 11 * 256 * 4;
    float* self0_tab = (float*)w; w += 11 * 256 * 4;
    float* msg0_tab  = (float*)w; w += 55 * 256 * 4;
    float* bondtab   = (float*)w; w += 2 * 5 * 256 * 4;
    u16* BtL1  = (u16*)w; w += 512 * 256 * 2;
    u16* BtL2  = (u16*)w; w += 512 * 256 * 2;
    u16* Bt3   = (u16*)w; w += 384 * 256 * 2;
    u16* BtW2  = (u16*)w; w += 128 * 128 * 2;
    u16* BtCP2 = (u16*)w; w += 128 * 128 * 2;
    float* bias512  = (float*)w; w += 2 * 512 * 4;
    float* biasPost = (float*)w; w += 384 * 4;

    // ---- setup ----
    k_type_mlp<<<1, 256, 0, stream>>>(atom_emb, vp_w1, vp_b1, vp_w2, vp_b2, pv_tab, vl_tab, h0_tab);
    k_tables<<<76, 256, 0, stream>>>(bond_emb, gnn_wself, gnn_bself, gnn_wmsg, gnn_bmsg,
                                     h0_tab, self0_tab, msg0_tab, bondtab);
    k_wtrans<<<1664, 256, 0, stream>>>(gnn_wmsg, gnn_wself, bc_w1, cp_w1, bc_w2, cp_w2,
                                       BtL1, BtL2, Bt3, BtW2, BtCP2);
    k_setup_bias<<<6, 256, 0, stream>>>(gnn_bself, bc_b1, cp_b1, bias512, biasPost);
    k_node_init<<<(N_NODES + 255) / 256, 256, 0, stream>>>(x, pv_tab, vl_tab, types, pvarr, degree, vl_out);
    k_edge_deg<<<(N_EDGES + 255) / 256, 256, 0, stream>>>(ei, degree);
    int nb = (N_NODES + SCAN_B - 1) / SCAN_B;
    k_scan1<<<nb, SCAN_B, 0, stream>>>(degree, offsets, bsum);
    k_scan2<<<1, 128, 0, stream>>>(bsum, bbase, nb);
    k_scan3<<<nb, SCAN_B, 0, stream>>>(offsets, bbase, cursor);
    k_csr_fill<<<(N_EDGES + 255) / 256, 256, 0, stream>>>(ei, edge_attr, types, cursor, csr, rowcsr, eidarr);
    k_agg0<<<N_NODES / 4, 256, 0, stream>>>(offsets, degree, types, self0_tab, msg0_tab, csr, h_bf);

    // ---- GNN layers 1,2 (l=2 fuses damp/viol/h_out) ----
    const int MT = M_PAD / 128;           // 782
    const int QB = (MT + 7) / 8;          // 98
    for (int l = 1; l <= 2; ++l) {
        const u16* BtL = (l == 1) ? BtL1 : BtL2;
        k_gemm_dual<<<QB * 32, 256, 0, stream>>>(h_bf, BtL, bias512 + (size_t)(l - 1) * 512,
                                                 hm_bf, hs_bf, N_NODES, MT);
        k_agg12<<<N_NODES / 4, 256, 0, stream>>>(offsets, degree, hs_bf, hm_bf,
                                                 bondtab + (size_t)(l - 1) * 5 * 256, csr, h_bf,
                                                 (l == 2) ? 1 : 0, pvarr, h_out, hd_bf, vi_out);
    }

    // ---- uv + cp1 fused; then cp2 ----
    k_gemm_post<<<QB * 24, 256, 0, stream>>>(hd_bf, Bt3, biasPost, uv_bf, cp1_bf, N_NODES, MT);
    k_gemm_k128<<<MT, 256, 0, stream>>>(cp1_bf, BtCP2, cp_b2, cp_out, 32, N_NODES, 32);

    // ---- fused bond chain ----
    k_bond_fused<<<E_PAD / 128, 256, 0, stream>>>(csr, rowcsr, eidarr, types, pvarr, pv_tab,
                                                  uv_bf, bc_w1, BtW2, bc_b2, bc_w3, bc_b3, bl_out);
}